// Round 1
// baseline (4055.859 us; speedup 1.0000x reference)
//
#include <hip/hip_runtime.h>
#include <math.h>

#define N_NODES 20000
#define N_EDGES 50000
#define NB      1024
#define IND     32
#define HDIM    64

static inline size_t align_up(size_t x, size_t a) { return (x + a - 1) & ~(a - 1); }

__device__ __forceinline__ float sigmoidf_(float x) {
    return 1.0f / (1.0f + __expf(-x));
}
__device__ __forceinline__ float tanhf_(float x) {
    float xc = fminf(fmaxf(x, -15.0f), 15.0f);
    float e = __expf(2.0f * xc);
    return (e - 1.0f) / (e + 1.0f);
}

// out[c*R + r] = in[r*C + c]   (in is [R][C], out is [C][R])
__global__ void k_transpose(const float* __restrict__ in, float* __restrict__ out, int R, int C) {
    int idx = blockIdx.x * 256 + threadIdx.x;
    if (idx >= R * C) return;
    int r = idx / C, c = idx - r * C;
    out[c * R + r] = in[idx];
}

// We2r[(h*64+k)*64 + o] = We2[k*4096 + h*64 + o]
__global__ void k_we2r(const float* __restrict__ We2, float* __restrict__ We2r) {
    int idx = blockIdx.x * 256 + threadIdx.x;   // 0..262143
    int o = idx & 63;
    int kh = idx >> 6;
    int k = kh & 63;
    int h = kh >> 6;
    We2r[idx] = We2[k * 4096 + h * 64 + o];
}

// offs[i] = lower_bound(batch, i) for i in [0, NB]
__global__ void k_offsets(const int* __restrict__ batch, int* __restrict__ offs) {
    int i = blockIdx.x * 256 + threadIdx.x;
    if (i > NB) return;
    int lo = 0, hi = N_NODES;
    while (lo < hi) { int mid = (lo + hi) >> 1; if (batch[mid] < i) lo = mid + 1; else hi = mid; }
    offs[i] = lo;
}

// hbuf[n][j] = relu(b0[j] + sum_i x[n][i]*W0[i][j]); 4 nodes / block (wave each)
__global__ void k_node_init(const float* __restrict__ x, const float* __restrict__ W0,
                            const float* __restrict__ b0, float* __restrict__ hbuf) {
    int tid = threadIdx.x;
    int w = tid >> 6, j = tid & 63;
    int n = blockIdx.x * 4 + w;
    float acc = b0[j];
    const float* xr = x + n * IND;
#pragma unroll
    for (int i = 0; i < IND; ++i) acc = fmaf(xr[i], W0[i * 64 + j], acc);
    hbuf[n * 64 + j] = fmaxf(acc, 0.0f);
}

// re[e][k] = relu(be1[k] + sum_i ea[e][i]*We1[i][k]); 4 edges / block
__global__ void k_edge_feat(const float* __restrict__ ea, const float* __restrict__ We1,
                            const float* __restrict__ be1, float* __restrict__ re) {
    int tid = threadIdx.x;
    int w = tid >> 6, k = tid & 63;
    int e = blockIdx.x * 4 + w;
    if (e >= N_EDGES) return;
    float acc = be1[k];
    const float* er = ea + e * 6;
#pragma unroll
    for (int i = 0; i < 6; ++i) acc = fmaf(er[i], We1[i * 64 + k], acc);
    re[e * 64 + k] = fmaxf(acc, 0.0f);
}

// The big one: per 64-edge tile, msg[e,o] = sum_{h,k} v[e,h]*re[e,k]*We2r[(h,k),o]
//                                           + sum_h v[e,h]*be2[h*64+o];  agg[dst[e]] += msg.
// 256 threads: 4x4 micro-tile per thread (edges x outputs). K streamed as 64 h-slabs of
// 64x64 B'-tiles, single LDS buffer + register prefetch (2 barriers per slab).
__launch_bounds__(256, 3)
__global__ void k_msg_scatter(const float* __restrict__ hbuf, const float* __restrict__ re,
                              const float* __restrict__ We2r, const float* __restrict__ be2,
                              const int* __restrict__ ei, float* __restrict__ agg) {
    __shared__ float s_v[64][64];     // [edge][h]
    __shared__ float s_re[64][68];    // [edge][k], padded (2-way max -> free)
    __shared__ float s_b[64 * 64];    // B' slab [k][o]
    __shared__ int   s_dst[64];
    int tid = threadIdx.x;
    int eb = blockIdx.x * 64;
#pragma unroll
    for (int r = 0; r < 16; ++r) {
        int idx = r * 256 + tid;
        int i = idx >> 6, c = idx & 63;
        int e = eb + i;
        float vv = 0.0f, rr = 0.0f;
        if (e < N_EDGES) {
            vv = hbuf[ei[e] * 64 + c];
            rr = re[e * 64 + c];
        }
        s_v[i][c] = vv;
        s_re[i][c] = rr;
    }
    if (tid < 64) {
        int e = eb + tid;
        s_dst[tid] = (e < N_EDGES) ? ei[N_EDGES + e] : -1;
    }
    int tx = tid & 15, ty = tid >> 4;
    int o0 = tx * 4, e0 = ty * 4;

    float4 pre0 = *(const float4*)&We2r[tid * 4];
    float4 pre1 = *(const float4*)&We2r[1024 + tid * 4];
    float4 pre2 = *(const float4*)&We2r[2048 + tid * 4];
    float4 pre3 = *(const float4*)&We2r[3072 + tid * 4];

    float acc[4][4] = {{0.f,0.f,0.f,0.f},{0.f,0.f,0.f,0.f},{0.f,0.f,0.f,0.f},{0.f,0.f,0.f,0.f}};

    for (int h = 0; h < 64; ++h) {
        __syncthreads();                       // prior slab reads done (and staging visible at h=0)
        *(float4*)&s_b[tid * 4]        = pre0;
        *(float4*)&s_b[1024 + tid * 4] = pre1;
        *(float4*)&s_b[2048 + tid * 4] = pre2;
        *(float4*)&s_b[3072 + tid * 4] = pre3;
        __syncthreads();                       // slab h visible
        if (h < 63) {
            const float* src = &We2r[(h + 1) * 4096];
            pre0 = *(const float4*)&src[tid * 4];
            pre1 = *(const float4*)&src[1024 + tid * 4];
            pre2 = *(const float4*)&src[2048 + tid * 4];
            pre3 = *(const float4*)&src[3072 + tid * 4];
        } else {                               // prefetch be2 slab for the bias pass
            pre0 = *(const float4*)&be2[tid * 4];
            pre1 = *(const float4*)&be2[1024 + tid * 4];
            pre2 = *(const float4*)&be2[2048 + tid * 4];
            pre3 = *(const float4*)&be2[3072 + tid * 4];
        }
        float vh[4];
#pragma unroll
        for (int i = 0; i < 4; ++i) vh[i] = s_v[e0 + i][h];
#pragma unroll
        for (int k = 0; k < 64; k += 4) {
            float a[4][4], bb[4][4];
#pragma unroll
            for (int i = 0; i < 4; ++i) {
                float4 t4 = *(const float4*)&s_re[e0 + i][k];
                a[i][0] = t4.x; a[i][1] = t4.y; a[i][2] = t4.z; a[i][3] = t4.w;
            }
#pragma unroll
            for (int m = 0; m < 4; ++m) {
                float4 t4 = *(const float4*)&s_b[(k + m) * 64 + o0];
                bb[m][0] = t4.x; bb[m][1] = t4.y; bb[m][2] = t4.z; bb[m][3] = t4.w;
            }
#pragma unroll
            for (int i = 0; i < 4; ++i)
#pragma unroll
                for (int m = 0; m < 4; ++m) {
                    float am = vh[i] * a[i][m];
#pragma unroll
                    for (int j = 0; j < 4; ++j) acc[i][j] = fmaf(am, bb[m][j], acc[i][j]);
                }
        }
    }
    // bias pass: acc[i][j] += sum_h v[e0+i][h] * be2[h*64+o0+j]
    __syncthreads();
    *(float4*)&s_b[tid * 4]        = pre0;
    *(float4*)&s_b[1024 + tid * 4] = pre1;
    *(float4*)&s_b[2048 + tid * 4] = pre2;
    *(float4*)&s_b[3072 + tid * 4] = pre3;
    __syncthreads();
#pragma unroll
    for (int k = 0; k < 64; k += 4) {
        float a[4][4], bb[4][4];
#pragma unroll
        for (int i = 0; i < 4; ++i) {
            float4 t4 = *(const float4*)&s_v[e0 + i][k];
            a[i][0] = t4.x; a[i][1] = t4.y; a[i][2] = t4.z; a[i][3] = t4.w;
        }
#pragma unroll
        for (int m = 0; m < 4; ++m) {
            float4 t4 = *(const float4*)&s_b[(k + m) * 64 + o0];
            bb[m][0] = t4.x; bb[m][1] = t4.y; bb[m][2] = t4.z; bb[m][3] = t4.w;
        }
#pragma unroll
        for (int i = 0; i < 4; ++i)
#pragma unroll
            for (int m = 0; m < 4; ++m) {
#pragma unroll
                for (int j = 0; j < 4; ++j) acc[i][j] = fmaf(a[i][m], bb[m][j], acc[i][j]);
            }
    }
    // scatter
#pragma unroll
    for (int i = 0; i < 4; ++i) {
        int e = eb + e0 + i;
        if (e < N_EDGES) {
            float* ap = agg + s_dst[e0 + i] * 64 + o0;
#pragma unroll
            for (int j = 0; j < 4; ++j)
                __hip_atomic_fetch_add(&ap[j], acc[i][j], __ATOMIC_RELAXED, __HIP_MEMORY_SCOPE_AGENT);
        }
    }
}

// m = relu(agg + h@Wroot + bconv); GRU(h, m) -> h.  4 nodes / block (wave each).
__global__ void k_node_update(float* __restrict__ hbuf, const float* __restrict__ agg,
                              const float* __restrict__ Wroot, const float* __restrict__ bconv,
                              const float* __restrict__ wihT, const float* __restrict__ whhT,
                              const float* __restrict__ bih, const float* __restrict__ bhh) {
    __shared__ float s_h[4][64];
    __shared__ float s_m[4][64];
    int tid = threadIdx.x;
    int w = tid >> 6, j = tid & 63;
    int n = blockIdx.x * 4 + w;
    float hv = hbuf[n * 64 + j];
    s_h[w][j] = hv;
    __syncthreads();
    float m = agg[n * 64 + j] + bconv[j];
#pragma unroll 8
    for (int i = 0; i < 64; ++i) m = fmaf(s_h[w][i], Wroot[i * 64 + j], m);
    m = fmaxf(m, 0.0f);
    s_m[w][j] = m;
    __syncthreads();
    float gi0 = bih[j], gi1 = bih[64 + j], gi2 = bih[128 + j];
    float gh0 = bhh[j], gh1 = bhh[64 + j], gh2 = bhh[128 + j];
#pragma unroll 4
    for (int i = 0; i < 64; ++i) {
        float mi = s_m[w][i], hi = s_h[w][i];
        const float* wr = wihT + i * 192 + j;
        const float* hr = whhT + i * 192 + j;
        gi0 = fmaf(mi, wr[0],   gi0);
        gi1 = fmaf(mi, wr[64],  gi1);
        gi2 = fmaf(mi, wr[128], gi2);
        gh0 = fmaf(hi, hr[0],   gh0);
        gh1 = fmaf(hi, hr[64],  gh1);
        gh2 = fmaf(hi, hr[128], gh2);
    }
    float r  = sigmoidf_(gi0 + gh0);
    float z  = sigmoidf_(gi1 + gh1);
    float nn = tanhf_(gi2 + r * gh2);
    hbuf[n * 64 + j] = (1.0f - z) * nn + z * hv;
}

// Set2Set LSTM step, one block (256 thr) per graph
__global__ void k_lstm(const float* __restrict__ q_star, float* __restrict__ qh, float* __restrict__ qc,
                       const float* __restrict__ l_wihT, const float* __restrict__ l_whhT,
                       const float* __restrict__ l_bih, const float* __restrict__ l_bhh) {
    __shared__ float s_qs[128];
    __shared__ float s_qh[64];
    __shared__ float s_g[256];
    int b = blockIdx.x;
    int j = threadIdx.x;
    if (j < 128) s_qs[j] = q_star[b * 128 + j];
    else if (j < 192) s_qh[j - 128] = qh[b * 64 + (j - 128)];
    __syncthreads();
    float g = l_bih[j] + l_bhh[j];
#pragma unroll 8
    for (int i = 0; i < 128; ++i) g = fmaf(s_qs[i], l_wihT[i * 256 + j], g);
#pragma unroll 8
    for (int i = 0; i < 64; ++i)  g = fmaf(s_qh[i], l_whhT[i * 256 + j], g);
    s_g[j] = g;
    __syncthreads();
    if (j < 64) {
        float ci = sigmoidf_(s_g[j]);
        float cf = sigmoidf_(s_g[64 + j]);
        float cg = tanhf_(s_g[128 + j]);
        float co = sigmoidf_(s_g[192 + j]);
        float c = cf * qc[b * 64 + j] + ci * cg;
        qc[b * 64 + j] = c;
        qh[b * 64 + j] = co * tanhf_(c);
    }
}

// per-graph online-softmax attention (batch sorted -> contiguous node ranges). 1 wave/graph.
__global__ void k_attention(const float* __restrict__ hbuf, const float* __restrict__ qh,
                            const int* __restrict__ offs, float* __restrict__ q_star) {
    int tid = threadIdx.x;
    int w = tid >> 6, lane = tid & 63;
    int b = blockIdx.x * 4 + w;
    int s = offs[b], e = offs[b + 1];
    float qv = qh[b * 64 + lane];
    float mx = -1e30f, l = 0.0f, racc = 0.0f;
    for (int n = s; n < e; ++n) {
        float xv = hbuf[n * 64 + lane];
        float prod = xv * qv;
#pragma unroll
        for (int off = 32; off > 0; off >>= 1) prod += __shfl_xor(prod, off);
        float mnew = fmaxf(mx, prod);
        float scale = __expf(mx - mnew);
        float wgt = __expf(prod - mnew);
        l = l * scale + wgt;
        racc = racc * scale + wgt * xv;
        mx = mnew;
    }
    float r = (e > s) ? (racc / l) : 0.0f;
    q_star[b * 128 + lane] = qv;
    q_star[b * 128 + 64 + lane] = r;
}

// readout MLP, 1 wave/graph
__global__ void k_readout(const float* __restrict__ q_star, const float* __restrict__ t,
                          const float* __restrict__ p, const float* __restrict__ W1,
                          const float* __restrict__ b1, const float* __restrict__ W2,
                          const float* __restrict__ b2, const float* __restrict__ W3,
                          const float* __restrict__ b3, float* __restrict__ y) {
    __shared__ float s_qs[4][128];
    __shared__ float s_y[4][64];
    int tid = threadIdx.x;
    int w = tid >> 6, j = tid & 63;
    int b = blockIdx.x * 4 + w;
    s_qs[w][j] = q_star[b * 128 + j];
    s_qs[w][64 + j] = q_star[b * 128 + 64 + j];
    __syncthreads();
    float acc = b1[j];
#pragma unroll 8
    for (int i = 0; i < 128; ++i) acc = fmaf(s_qs[w][i], W1[i * 64 + j], acc);
    acc = fmaf(t[b], W1[128 * 64 + j], acc);
    acc = fmaf(p[b], W1[129 * 64 + j], acc);
    acc = fmaxf(acc, 0.0f);
    s_y[w][j] = acc;
    __syncthreads();
    float acc2 = b2[j];
#pragma unroll 8
    for (int i = 0; i < 64; ++i) acc2 = fmaf(s_y[w][i], W2[i * 64 + j], acc2);
    acc2 = fmaxf(acc2, 0.0f);
    float part = acc2 * W3[j];
#pragma unroll
    for (int off = 32; off > 0; off >>= 1) part += __shfl_xor(part, off);
    if (j == 0) y[b] = part + b3[0];
}

extern "C" void kernel_launch(void* const* d_in, const int* in_sizes, int n_in,
                              void* d_out, int out_size, void* d_ws, size_t ws_size,
                              hipStream_t stream) {
    const float* x     = (const float*)d_in[0];
    const int*   ei    = (const int*)  d_in[1];
    const float* ea    = (const float*)d_in[2];
    const int*   batch = (const int*)  d_in[3];
    const float* t     = (const float*)d_in[4];
    const float* p     = (const float*)d_in[5];
    const float* W0    = (const float*)d_in[7];
    const float* b0    = (const float*)d_in[8];
    const float* We1   = (const float*)d_in[9];
    const float* be1   = (const float*)d_in[10];
    const float* We2   = (const float*)d_in[11];
    const float* be2   = (const float*)d_in[12];
    const float* Wroot = (const float*)d_in[13];
    const float* bconv = (const float*)d_in[14];
    const float* gwih  = (const float*)d_in[15];
    const float* gwhh  = (const float*)d_in[16];
    const float* gbih  = (const float*)d_in[17];
    const float* gbhh  = (const float*)d_in[18];
    const float* lwih  = (const float*)d_in[19];
    const float* lwhh  = (const float*)d_in[20];
    const float* lbih  = (const float*)d_in[21];
    const float* lbhh  = (const float*)d_in[22];
    const float* W1    = (const float*)d_in[23];
    const float* b1    = (const float*)d_in[24];
    const float* W2    = (const float*)d_in[25];
    const float* b2    = (const float*)d_in[26];
    const float* W3    = (const float*)d_in[27];
    const float* b3    = (const float*)d_in[28];
    float* y = (float*)d_out;

    char* ws = (char*)d_ws;
    size_t off = 0;
    auto alloc = [&](size_t nfloats) {
        float* ptr = (float*)(ws + off);
        off += align_up(nfloats * 4, 256);
        return ptr;
    };
    float* hbuf  = alloc((size_t)N_NODES * 64);
    float* reb   = alloc((size_t)N_EDGES * 64);
    float* We2r  = alloc(262144);
    float* agg   = alloc((size_t)N_NODES * 64);
    float* wihT  = alloc(64 * 192);
    float* whhT  = alloc(64 * 192);
    float* lwihT = alloc(128 * 256);
    float* lwhhT = alloc(64 * 256);
    float* qh    = alloc(NB * 64);
    float* qc    = alloc(NB * 64);
    float* qstar = alloc(NB * 128);
    int*   offs  = (int*)alloc(NB + 1);

    // ---- prep: weight transposes, We2 permute, per-graph offsets, zero state
    k_transpose<<<(192 * 64 + 255) / 256, 256, 0, stream>>>(gwih, wihT, 192, 64);
    k_transpose<<<(192 * 64 + 255) / 256, 256, 0, stream>>>(gwhh, whhT, 192, 64);
    k_transpose<<<(256 * 128 + 255) / 256, 256, 0, stream>>>(lwih, lwihT, 256, 128);
    k_transpose<<<(256 * 64 + 255) / 256, 256, 0, stream>>>(lwhh, lwhhT, 256, 64);
    k_we2r<<<1024, 256, 0, stream>>>(We2, We2r);
    k_offsets<<<5, 256, 0, stream>>>(batch, offs);
    hipMemsetAsync(qh, 0, (size_t)(NB * 64 + NB * 64 + NB * 128) * 4, stream); // qh|qc|qstar contiguous

    // ---- encoder
    k_node_init<<<N_NODES / 4, 256, 0, stream>>>(x, W0, b0, hbuf);
    k_edge_feat<<<N_EDGES / 4, 256, 0, stream>>>(ea, We1, be1, reb);

    // ---- 4 message-passing + GRU iterations
    for (int it = 0; it < 4; ++it) {
        hipMemsetAsync(agg, 0, (size_t)N_NODES * 64 * 4, stream);
        k_msg_scatter<<<(N_EDGES + 63) / 64, 256, 0, stream>>>(hbuf, reb, We2r, be2, ei, agg);
        k_node_update<<<N_NODES / 4, 256, 0, stream>>>(hbuf, agg, Wroot, bconv, wihT, whhT, gbih, gbhh);
    }

    // ---- Set2Set, 3 steps
    for (int itr = 0; itr < 3; ++itr) {
        k_lstm<<<NB, 256, 0, stream>>>(qstar, qh, qc, lwihT, lwhhT, lbih, lbhh);
        k_attention<<<NB / 4, 256, 0, stream>>>(hbuf, qh, offs, qstar);
    }

    // ---- readout
    k_readout<<<NB / 4, 256, 0, stream>>>(qstar, t, p, W1, b1, W2, b2, W3, b3, y);
}

// Round 2
// 835.499 us; speedup vs baseline: 4.8544x; 4.8544x over previous
//
#include <hip/hip_runtime.h>
#include <math.h>

#define N_NODES 20000
#define N_EDGES 50000
#define NB      1024
#define IND     32
#define HDIM    64

typedef __attribute__((ext_vector_type(8))) short bf16x8;
typedef __attribute__((ext_vector_type(4))) float f32x4;

static inline size_t align_up(size_t x, size_t a) { return (x + a - 1) & ~(a - 1); }

__device__ __forceinline__ float sigmoidf_(float x) {
    return 1.0f / (1.0f + __expf(-x));
}
__device__ __forceinline__ float tanhf_(float x) {
    float xc = fminf(fmaxf(x, -15.0f), 15.0f);
    float e = __expf(2.0f * xc);
    return (e - 1.0f) / (e + 1.0f);
}
// pack two fp32 -> dword of two bf16 (round-half-up; inputs finite)
__device__ __forceinline__ unsigned pk2(float p0, float p1) {
    unsigned u0 = __float_as_uint(p0) + 0x8000u;
    unsigned u1 = __float_as_uint(p1) + 0x8000u;
    return __builtin_amdgcn_perm(u1, u0, 0x07060302u);
}

// out[c*R + r] = in[r*C + c]
__global__ void k_transpose(const float* __restrict__ in, float* __restrict__ out, int R, int C) {
    int idx = blockIdx.x * 256 + threadIdx.x;
    if (idx >= R * C) return;
    int r = idx / C, c = idx - r * C;
    out[c * R + r] = in[idx];
}

// We2b: 65 slabs of 4096 bf16, fragment-ordered for 16x16x32 MFMA B-operand.
// slab s<64: B_s[k][o] = We2[k*4096 + s*64 + o]; slab 64: B[k][o] = be2[k*64+o].
// dest short idx = s*4096 + ((o>>4)*128 + (k>>5)*64 + ((k>>3)&3)*16 + (o&15))*8 + (k&7)
__global__ void k_we2b(const float* __restrict__ We2, const float* __restrict__ be2,
                       short* __restrict__ We2b) {
    int idx = blockIdx.x * 256 + threadIdx.x;     // 0 .. 65*4096-1
    int s = idx >> 12;
    int col = idx & 4095;
    int k = col >> 6, o = col & 63;
    float val = (s < 64) ? We2[k * 4096 + s * 64 + o] : be2[k * 64 + o];
    unsigned u = __float_as_uint(val) + 0x8000u;
    int dst = s * 4096 + (((o >> 4) * 128 + (k >> 5) * 64 + ((k >> 3) & 3) * 16 + (o & 15)) << 3) + (k & 7);
    We2b[dst] = (short)(u >> 16);
}

// offs[i] = lower_bound(batch, i)
__global__ void k_offsets(const int* __restrict__ batch, int* __restrict__ offs) {
    int i = blockIdx.x * 256 + threadIdx.x;
    if (i > NB) return;
    int lo = 0, hi = N_NODES;
    while (lo < hi) { int mid = (lo + hi) >> 1; if (batch[mid] < i) lo = mid + 1; else hi = mid; }
    offs[i] = lo;
}

// ---- CSR build: deg count -> 1-block scan -> fill ----
__global__ void k_count(const int* __restrict__ ei, int* __restrict__ deg) {
    int e = blockIdx.x * 256 + threadIdx.x;
    if (e < N_EDGES) atomicAdd(&deg[ei[N_EDGES + e]], 1);
}

__global__ void k_scan(const int* __restrict__ deg, int* __restrict__ rowptr, int* __restrict__ cursor) {
    __shared__ int s_w[16];
    int t = threadIdx.x;            // 0..1023
    int base = t * 20;
    int v[20]; int s = 0;
#pragma unroll
    for (int i = 0; i < 20; ++i) {
        int idx = base + i;
        v[i] = (idx < N_NODES) ? deg[idx] : 0;
        s += v[i];
    }
    int lane = t & 63, w = t >> 6;
    int inc = s;
#pragma unroll
    for (int off = 1; off < 64; off <<= 1) {
        int o = __shfl_up(inc, off);
        if (lane >= off) inc += o;
    }
    if (lane == 63) s_w[w] = inc;
    __syncthreads();
    if (w == 0 && lane < 16) {
        int x = s_w[lane];
        int xs = x;
#pragma unroll
        for (int off = 1; off < 16; off <<= 1) {
            int o = __shfl_up(xs, off);
            if (lane >= off) xs += o;
        }
        s_w[lane] = xs - x;   // exclusive
    }
    __syncthreads();
    int run = s_w[w] + (inc - s);   // exclusive prefix for this thread's chunk
#pragma unroll
    for (int i = 0; i < 20; ++i) {
        int idx = base + i;
        if (idx < N_NODES) { rowptr[idx] = run; cursor[idx] = run; }
        else if (idx == N_NODES) rowptr[idx] = run;
        run += v[i];
    }
}

__global__ void k_fill(const int* __restrict__ ei, int* __restrict__ cursor, int* __restrict__ perm) {
    int e = blockIdx.x * 256 + threadIdx.x;
    if (e < N_EDGES) {
        int pos = atomicAdd(&cursor[ei[N_EDGES + e]], 1);
        perm[pos] = e;
    }
}

// hbuf[n][j] = relu(b0[j] + sum_i x[n][i]*W0[i][j])
__global__ void k_node_init(const float* __restrict__ x, const float* __restrict__ W0,
                            const float* __restrict__ b0, float* __restrict__ hbuf) {
    int tid = threadIdx.x;
    int w = tid >> 6, j = tid & 63;
    int n = blockIdx.x * 4 + w;
    float acc = b0[j];
    const float* xr = x + n * IND;
#pragma unroll
    for (int i = 0; i < IND; ++i) acc = fmaf(xr[i], W0[i * 64 + j], acc);
    hbuf[n * 64 + j] = fmaxf(acc, 0.0f);
}

// re[e][k] = relu(be1[k] + sum_i ea[e][i]*We1[i][k])
__global__ void k_edge_feat(const float* __restrict__ ea, const float* __restrict__ We1,
                            const float* __restrict__ be1, float* __restrict__ re) {
    int tid = threadIdx.x;
    int w = tid >> 6, k = tid & 63;
    int e = blockIdx.x * 4 + w;
    if (e >= N_EDGES) return;
    float acc = be1[k];
    const float* er = ea + e * 6;
#pragma unroll
    for (int i = 0; i < 6; ++i) acc = fmaf(er[i], We1[i * 64 + k], acc);
    re[e * 64 + k] = fmaxf(acc, 0.0f);
}

// MFMA message kernel: per 64-edge tile, msg[e,o] = sum_{h,k} v[e,h]*re[e,k]*W[h,k,o] + sum_h v[e,h]*be2[h,o]
// Wave w computes outputs o in [16w,16w+16) for all 64 edges. A-fragments built in registers
// (re in VGPRs, v via LDS broadcast); B-fragments loaded from L2-resident We2b (no LDS staging).
__launch_bounds__(256, 3)
__global__ void k_msg_mfma(const float* __restrict__ hbuf, const float* __restrict__ reb,
                           const short* __restrict__ We2b, const int* __restrict__ ei,
                           float* __restrict__ msg) {
    __shared__ float s_v[64][64];    // [h][e] transposed: conflict-free broadcast reads
    int tid = threadIdx.x;
    int eb = blockIdx.x * 64;
    int lane = tid & 63;
    int w = tid >> 6;                 // wave id = output n-tile
    int l15 = lane & 15, lhi = lane >> 4;

    // ---- stage s_v (transposed) ----
    {
        int se = tid >> 2;            // edge slot 0..63
        int sh = tid & 3;             // 16B chunk in row
        int ge = eb + se;
        const float* rowp = (ge < N_EDGES) ? (hbuf + (size_t)ei[ge] * 64) : (const float*)0;
#pragma unroll
        for (int rr4 = 0; rr4 < 4; ++rr4) {
            int hb = rr4 * 16 + sh * 4;
            float4 vv = rowp ? *(const float4*)(rowp + hb) : make_float4(0.f, 0.f, 0.f, 0.f);
            s_v[hb + 0][se] = vv.x; s_v[hb + 1][se] = vv.y;
            s_v[hb + 2][se] = vv.z; s_v[hb + 3][se] = vv.w;
        }
    }

    // ---- re into registers: re_r[mtile][chunk][j] = reb[e][c*32 + lhi*8 + j] ----
    float re_r[4][2][8];
#pragma unroll
    for (int m = 0; m < 4; ++m) {
        int ge = eb + m * 16 + l15;
        if (ge < N_EDGES) {
            const float* rp = reb + (size_t)ge * 64 + lhi * 8;
            float4 x0 = *(const float4*)(rp);
            float4 x1 = *(const float4*)(rp + 4);
            float4 y0 = *(const float4*)(rp + 32);
            float4 y1 = *(const float4*)(rp + 36);
            re_r[m][0][0] = x0.x; re_r[m][0][1] = x0.y; re_r[m][0][2] = x0.z; re_r[m][0][3] = x0.w;
            re_r[m][0][4] = x1.x; re_r[m][0][5] = x1.y; re_r[m][0][6] = x1.z; re_r[m][0][7] = x1.w;
            re_r[m][1][0] = y0.x; re_r[m][1][1] = y0.y; re_r[m][1][2] = y0.z; re_r[m][1][3] = y0.w;
            re_r[m][1][4] = y1.x; re_r[m][1][5] = y1.y; re_r[m][1][6] = y1.z; re_r[m][1][7] = y1.w;
        } else {
#pragma unroll
            for (int c = 0; c < 2; ++c)
#pragma unroll
                for (int j = 0; j < 8; ++j) re_r[m][c][j] = 0.0f;
        }
    }
    __syncthreads();

    // ---- K loop over 64 h-slabs + bias slab, B prefetched one slab ahead ----
    const int4* bp0 = (const int4*)We2b + (w * 128 + lane);   // chunk 0; slab stride = 512 int4
    const int4* bp1 = bp0 + 64;                                // chunk 1
    int4 b0 = bp0[0], b1 = bp1[0];
    f32x4 acc[4];
#pragma unroll
    for (int m = 0; m < 4; ++m) acc[m] = (f32x4){0.f, 0.f, 0.f, 0.f};

    for (int h = 0; h < 64; ++h) {
        int4 nb0 = bp0[(h + 1) * 512];        // h==63 prefetches bias slab (s=64)
        int4 nb1 = bp1[(h + 1) * 512];
        float vmx[4];
        vmx[0] = s_v[h][l15];
        vmx[1] = s_v[h][16 + l15];
        vmx[2] = s_v[h][32 + l15];
        vmx[3] = s_v[h][48 + l15];
#pragma unroll
        for (int m = 0; m < 4; ++m) {
            float vm = vmx[m];
#pragma unroll
            for (int c = 0; c < 2; ++c) {
                const float* rr = re_r[m][c];
                union { int4 i4; bf16x8 v; } a;
                a.i4.x = pk2(vm * rr[0], vm * rr[1]);
                a.i4.y = pk2(vm * rr[2], vm * rr[3]);
                a.i4.z = pk2(vm * rr[4], vm * rr[5]);
                a.i4.w = pk2(vm * rr[6], vm * rr[7]);
                union { int4 i4; bf16x8 v; } b;
                b.i4 = c ? b1 : b0;
                acc[m] = __builtin_amdgcn_mfma_f32_16x16x32_bf16(a.v, b.v, acc[m], 0, 0, 0);
            }
        }
        b0 = nb0; b1 = nb1;
    }
    // ---- bias slab: A[e][kk] = v[e][kk] straight from s_v ----
#pragma unroll
    for (int m = 0; m < 4; ++m) {
        int e = m * 16 + l15;
#pragma unroll
        for (int c = 0; c < 2; ++c) {
            int kb = c * 32 + lhi * 8;
            union { int4 i4; bf16x8 v; } a;
            a.i4.x = pk2(s_v[kb + 0][e], s_v[kb + 1][e]);
            a.i4.y = pk2(s_v[kb + 2][e], s_v[kb + 3][e]);
            a.i4.z = pk2(s_v[kb + 4][e], s_v[kb + 5][e]);
            a.i4.w = pk2(s_v[kb + 6][e], s_v[kb + 7][e]);
            union { int4 i4; bf16x8 v; } b;
            b.i4 = c ? b1 : b0;
            acc[m] = __builtin_amdgcn_mfma_f32_16x16x32_bf16(a.v, b.v, acc[m], 0, 0, 0);
        }
    }
    // ---- store msg (coalesced per 16-lane group) ----
    int o = w * 16 + l15;
#pragma unroll
    for (int m = 0; m < 4; ++m) {
#pragma unroll
        for (int r = 0; r < 4; ++r) {
            int el = m * 16 + lhi * 4 + r;
            int ge = eb + el;
            if (ge < N_EDGES) msg[(size_t)ge * 64 + o] = acc[m][r];
        }
    }
}

// fused: m = relu(sum_{e->n} msg[e] + h@Wroot + bconv); GRU(h,m) -> h. 4 nodes/block.
__global__ void k_node_update(float* __restrict__ hbuf, const float* __restrict__ msg,
                              const int* __restrict__ rowptr, const int* __restrict__ perm,
                              const float* __restrict__ Wroot, const float* __restrict__ bconv,
                              const float* __restrict__ wihT, const float* __restrict__ whhT,
                              const float* __restrict__ bih, const float* __restrict__ bhh) {
    __shared__ float s_h[4][64];
    __shared__ float s_m[4][64];
    int tid = threadIdx.x;
    int w = tid >> 6, j = tid & 63;
    int n = blockIdx.x * 4 + w;
    float hv = hbuf[n * 64 + j];
    s_h[w][j] = hv;
    __syncthreads();
    float m = bconv[j];
    int rs = rowptr[n], rend = rowptr[n + 1];
    for (int q = rs; q < rend; ++q) m += msg[(size_t)perm[q] * 64 + j];
#pragma unroll 8
    for (int i = 0; i < 64; ++i) m = fmaf(s_h[w][i], Wroot[i * 64 + j], m);
    m = fmaxf(m, 0.0f);
    s_m[w][j] = m;
    __syncthreads();
    float gi0 = bih[j], gi1 = bih[64 + j], gi2 = bih[128 + j];
    float gh0 = bhh[j], gh1 = bhh[64 + j], gh2 = bhh[128 + j];
#pragma unroll 4
    for (int i = 0; i < 64; ++i) {
        float mi = s_m[w][i], hi = s_h[w][i];
        const float* wr = wihT + i * 192 + j;
        const float* hr = whhT + i * 192 + j;
        gi0 = fmaf(mi, wr[0],   gi0);
        gi1 = fmaf(mi, wr[64],  gi1);
        gi2 = fmaf(mi, wr[128], gi2);
        gh0 = fmaf(hi, hr[0],   gh0);
        gh1 = fmaf(hi, hr[64],  gh1);
        gh2 = fmaf(hi, hr[128], gh2);
    }
    float r  = sigmoidf_(gi0 + gh0);
    float z  = sigmoidf_(gi1 + gh1);
    float nn = tanhf_(gi2 + r * gh2);
    hbuf[n * 64 + j] = (1.0f - z) * nn + z * hv;
}

// Set2Set LSTM step, one block (256 thr) per graph
__global__ void k_lstm(const float* __restrict__ q_star, float* __restrict__ qh, float* __restrict__ qc,
                       const float* __restrict__ l_wihT, const float* __restrict__ l_whhT,
                       const float* __restrict__ l_bih, const float* __restrict__ l_bhh) {
    __shared__ float s_qs[128];
    __shared__ float s_qh[64];
    __shared__ float s_g[256];
    int b = blockIdx.x;
    int j = threadIdx.x;
    if (j < 128) s_qs[j] = q_star[b * 128 + j];
    else if (j < 192) s_qh[j - 128] = qh[b * 64 + (j - 128)];
    __syncthreads();
    float g = l_bih[j] + l_bhh[j];
#pragma unroll 8
    for (int i = 0; i < 128; ++i) g = fmaf(s_qs[i], l_wihT[i * 256 + j], g);
#pragma unroll 8
    for (int i = 0; i < 64; ++i)  g = fmaf(s_qh[i], l_whhT[i * 256 + j], g);
    s_g[j] = g;
    __syncthreads();
    if (j < 64) {
        float ci = sigmoidf_(s_g[j]);
        float cf = sigmoidf_(s_g[64 + j]);
        float cg = tanhf_(s_g[128 + j]);
        float co = sigmoidf_(s_g[192 + j]);
        float c = cf * qc[b * 64 + j] + ci * cg;
        qc[b * 64 + j] = c;
        qh[b * 64 + j] = co * tanhf_(c);
    }
}

// per-graph online-softmax attention. 1 wave/graph.
__global__ void k_attention(const float* __restrict__ hbuf, const float* __restrict__ qh,
                            const int* __restrict__ offs, float* __restrict__ q_star) {
    int tid = threadIdx.x;
    int w = tid >> 6, lane = tid & 63;
    int b = blockIdx.x * 4 + w;
    int s = offs[b], e = offs[b + 1];
    float qv = qh[b * 64 + lane];
    float mx = -1e30f, l = 0.0f, racc = 0.0f;
    for (int n = s; n < e; ++n) {
        float xv = hbuf[n * 64 + lane];
        float prod = xv * qv;
#pragma unroll
        for (int off = 32; off > 0; off >>= 1) prod += __shfl_xor(prod, off);
        float mnew = fmaxf(mx, prod);
        float scale = __expf(mx - mnew);
        float wgt = __expf(prod - mnew);
        l = l * scale + wgt;
        racc = racc * scale + wgt * xv;
        mx = mnew;
    }
    float r = (e > s) ? (racc / l) : 0.0f;
    q_star[b * 128 + lane] = qv;
    q_star[b * 128 + 64 + lane] = r;
}

// readout MLP, 1 wave/graph
__global__ void k_readout(const float* __restrict__ q_star, const float* __restrict__ t,
                          const float* __restrict__ p, const float* __restrict__ W1,
                          const float* __restrict__ b1, const float* __restrict__ W2,
                          const float* __restrict__ b2, const float* __restrict__ W3,
                          const float* __restrict__ b3, float* __restrict__ y) {
    __shared__ float s_qs[4][128];
    __shared__ float s_y[4][64];
    int tid = threadIdx.x;
    int w = tid >> 6, j = tid & 63;
    int b = blockIdx.x * 4 + w;
    s_qs[w][j] = q_star[b * 128 + j];
    s_qs[w][64 + j] = q_star[b * 128 + 64 + j];
    __syncthreads();
    float acc = b1[j];
#pragma unroll 8
    for (int i = 0; i < 128; ++i) acc = fmaf(s_qs[w][i], W1[i * 64 + j], acc);
    acc = fmaf(t[b], W1[128 * 64 + j], acc);
    acc = fmaf(p[b], W1[129 * 64 + j], acc);
    acc = fmaxf(acc, 0.0f);
    s_y[w][j] = acc;
    __syncthreads();
    float acc2 = b2[j];
#pragma unroll 8
    for (int i = 0; i < 64; ++i) acc2 = fmaf(s_y[w][i], W2[i * 64 + j], acc2);
    acc2 = fmaxf(acc2, 0.0f);
    float part = acc2 * W3[j];
#pragma unroll
    for (int off = 32; off > 0; off >>= 1) part += __shfl_xor(part, off);
    if (j == 0) y[b] = part + b3[0];
}

extern "C" void kernel_launch(void* const* d_in, const int* in_sizes, int n_in,
                              void* d_out, int out_size, void* d_ws, size_t ws_size,
                              hipStream_t stream) {
    const float* x     = (const float*)d_in[0];
    const int*   ei    = (const int*)  d_in[1];
    const float* ea    = (const float*)d_in[2];
    const int*   batch = (const int*)  d_in[3];
    const float* t     = (const float*)d_in[4];
    const float* p     = (const float*)d_in[5];
    const float* W0    = (const float*)d_in[7];
    const float* b0    = (const float*)d_in[8];
    const float* We1   = (const float*)d_in[9];
    const float* be1   = (const float*)d_in[10];
    const float* We2   = (const float*)d_in[11];
    const float* be2   = (const float*)d_in[12];
    const float* Wroot = (const float*)d_in[13];
    const float* bconv = (const float*)d_in[14];
    const float* gwih  = (const float*)d_in[15];
    const float* gwhh  = (const float*)d_in[16];
    const float* gbih  = (const float*)d_in[17];
    const float* gbhh  = (const float*)d_in[18];
    const float* lwih  = (const float*)d_in[19];
    const float* lwhh  = (const float*)d_in[20];
    const float* lbih  = (const float*)d_in[21];
    const float* lbhh  = (const float*)d_in[22];
    const float* W1    = (const float*)d_in[23];
    const float* b1    = (const float*)d_in[24];
    const float* W2    = (const float*)d_in[25];
    const float* b2    = (const float*)d_in[26];
    const float* W3    = (const float*)d_in[27];
    const float* b3    = (const float*)d_in[28];
    float* y = (float*)d_out;

    char* ws = (char*)d_ws;
    size_t off = 0;
    auto alloc = [&](size_t nbytes) {
        void* ptr = (void*)(ws + off);
        off += align_up(nbytes, 256);
        return ptr;
    };
    float* hbuf   = (float*)alloc((size_t)N_NODES * 64 * 4);
    float* reb    = (float*)alloc((size_t)N_EDGES * 64 * 4);
    float* msg    = (float*)alloc((size_t)N_EDGES * 64 * 4);
    short* We2b   = (short*)alloc((size_t)65 * 4096 * 2);
    float* wihT   = (float*)alloc(64 * 192 * 4);
    float* whhT   = (float*)alloc(64 * 192 * 4);
    float* lwihT  = (float*)alloc(128 * 256 * 4);
    float* lwhhT  = (float*)alloc(64 * 256 * 4);
    float* qh     = (float*)alloc(NB * 64 * 4);
    float* qc     = (float*)alloc(NB * 64 * 4);
    float* qstar  = (float*)alloc(NB * 128 * 4);
    int*   offs   = (int*)  alloc((NB + 1) * 4);
    int*   deg    = (int*)  alloc(N_NODES * 4);
    int*   rowptr = (int*)  alloc((N_NODES + 1) * 4);
    int*   cursor = (int*)  alloc(N_NODES * 4);
    int*   perm   = (int*)  alloc(N_EDGES * 4);

    // ---- prep ----
    k_transpose<<<(192 * 64 + 255) / 256, 256, 0, stream>>>(gwih, wihT, 192, 64);
    k_transpose<<<(192 * 64 + 255) / 256, 256, 0, stream>>>(gwhh, whhT, 192, 64);
    k_transpose<<<(256 * 128 + 255) / 256, 256, 0, stream>>>(lwih, lwihT, 256, 128);
    k_transpose<<<(256 * 64 + 255) / 256, 256, 0, stream>>>(lwhh, lwhhT, 256, 64);
    k_we2b<<<65 * 4096 / 256, 256, 0, stream>>>(We2, be2, We2b);
    k_offsets<<<5, 256, 0, stream>>>(batch, offs);
    hipMemsetAsync(qh, 0, (size_t)(NB * 64 + NB * 64 + NB * 128) * 4, stream); // qh|qc|qstar contiguous
    hipMemsetAsync(deg, 0, (size_t)N_NODES * 4, stream);
    k_count<<<(N_EDGES + 255) / 256, 256, 0, stream>>>(ei, deg);
    k_scan<<<1, 1024, 0, stream>>>(deg, rowptr, cursor);
    k_fill<<<(N_EDGES + 255) / 256, 256, 0, stream>>>(ei, cursor, perm);

    // ---- encoder ----
    k_node_init<<<N_NODES / 4, 256, 0, stream>>>(x, W0, b0, hbuf);
    k_edge_feat<<<N_EDGES / 4, 256, 0, stream>>>(ea, We1, be1, reb);

    // ---- 4 message-passing + GRU iterations ----
    for (int it = 0; it < 4; ++it) {
        k_msg_mfma<<<(N_EDGES + 63) / 64, 256, 0, stream>>>(hbuf, reb, We2b, ei, msg);
        k_node_update<<<N_NODES / 4, 256, 0, stream>>>(hbuf, msg, rowptr, perm,
                                                       Wroot, bconv, wihT, whhT, gbih, gbhh);
    }

    // ---- Set2Set, 3 steps ----
    for (int itr = 0; itr < 3; ++itr) {
        k_lstm<<<NB, 256, 0, stream>>>(qstar, qh, qc, lwihT, lwhhT, lbih, lbhh);
        k_attention<<<NB / 4, 256, 0, stream>>>(hbuf, qh, offs, qstar);
    }

    // ---- readout ----
    k_readout<<<NB / 4, 256, 0, stream>>>(qstar, t, p, W1, b1, W2, b2, W3, b3, y);
}

// Round 4
// 504.133 us; speedup vs baseline: 8.0452x; 1.6573x over previous
//
#include <hip/hip_runtime.h>
#include <math.h>

#define N_NODES 20000
#define N_EDGES 50000
#define NB      1024
#define IND     32
#define HDIM    64

typedef __attribute__((ext_vector_type(8))) short bf16x8;
typedef __attribute__((ext_vector_type(4))) float f32x4;

static inline size_t align_up(size_t x, size_t a) { return (x + a - 1) & ~(a - 1); }

__device__ __forceinline__ float sigmoidf_(float x) {
    return 1.0f / (1.0f + __expf(-x));
}
__device__ __forceinline__ float tanhf_(float x) {
    float xc = fminf(fmaxf(x, -15.0f), 15.0f);
    float e = __expf(2.0f * xc);
    return (e - 1.0f) / (e + 1.0f);
}
// pack two fp32 -> dword of two bf16 (round-half-up)
__device__ __forceinline__ unsigned pk2(float p0, float p1) {
    unsigned u0 = __float_as_uint(p0) + 0x8000u;
    unsigned u1 = __float_as_uint(p1) + 0x8000u;
    return __builtin_amdgcn_perm(u1, u0, 0x07060302u);
}
__device__ __forceinline__ unsigned bf1(float v) {
    return (__float_as_uint(v) + 0x8000u) >> 16;
}

// out[c*R + r] = in[r*C + c]
__global__ void k_transpose(const float* __restrict__ in, float* __restrict__ out, int R, int C) {
    int idx = blockIdx.x * 256 + threadIdx.x;
    if (idx >= R * C) return;
    int r = idx / C, c = idx - r * C;
    out[c * R + r] = in[idx];
}

// We2b: 65 slabs of 4096 bf16, fragment-ordered for 16x16x32 MFMA B-operand.
// slab s<64: B_s[k][o] = We2[k*4096 + s*64 + o]; slab 64: B[k][o] = be2[k*64+o].
__global__ void k_we2b(const float* __restrict__ We2, const float* __restrict__ be2,
                       short* __restrict__ We2b) {
    int idx = blockIdx.x * 256 + threadIdx.x;     // 0 .. 65*4096-1
    int s = idx >> 12;
    int col = idx & 4095;
    int k = col >> 6, o = col & 63;
    float val = (s < 64) ? We2[k * 4096 + s * 64 + o] : be2[k * 64 + o];
    int dst = s * 4096 + (((o >> 4) * 128 + (k >> 5) * 64 + ((k >> 3) & 3) * 16 + (o & 15)) << 3) + (k & 7);
    We2b[dst] = (short)bf1(val);
}

// split-bf16 fragment-ordered weights for node update.
// WB1 (16384 shorts): B1[k][o], o<64: Wroot[k][o]; o in [64,256): whh[(o-64)][k]
// WB2 (12288 shorts): B2[k][o] = wih[o][k], o in [0,192)
// linear idx = ((otile*2 + c)*64 + lane)*8 + j ; k = c*32 + (lane>>4)*8 + j ; o = otile*16 + (lane&15)
__global__ void k_wsplit(const float* __restrict__ Wroot, const float* __restrict__ gwhh,
                         const float* __restrict__ gwih,
                         short* __restrict__ WB1h, short* __restrict__ WB1l,
                         short* __restrict__ WB2h, short* __restrict__ WB2l) {
    int idx = blockIdx.x * 256 + threadIdx.x;   // 0..28671
    if (idx >= 28672) return;
    bool b1 = idx < 16384;
    int li = b1 ? idx : idx - 16384;
    int j = li & 7, lane = (li >> 3) & 63, c = (li >> 9) & 1, otile = li >> 10;
    int k = c * 32 + (lane >> 4) * 8 + j;
    int o = otile * 16 + (lane & 15);
    float val;
    if (b1) val = (o < 64) ? Wroot[k * 64 + o] : gwhh[(o - 64) * 64 + k];
    else    val = gwih[o * 64 + k];
    unsigned hs = bf1(val);
    float lo = val - __uint_as_float(hs << 16);
    unsigned ls = bf1(lo);
    if (b1) { WB1h[li] = (short)hs; WB1l[li] = (short)ls; }
    else    { WB2h[li] = (short)hs; WB2l[li] = (short)ls; }
}

// offs[i] = lower_bound(batch, i)
__global__ void k_offsets(const int* __restrict__ batch, int* __restrict__ offs) {
    int i = blockIdx.x * 256 + threadIdx.x;
    if (i > NB) return;
    int lo = 0, hi = N_NODES;
    while (lo < hi) { int mid = (lo + hi) >> 1; if (batch[mid] < i) lo = mid + 1; else hi = mid; }
    offs[i] = lo;
}

// ---- CSR build ----
__global__ void k_count(const int* __restrict__ ei, int* __restrict__ deg) {
    int e = blockIdx.x * 256 + threadIdx.x;
    if (e < N_EDGES) atomicAdd(&deg[ei[N_EDGES + e]], 1);
}

__global__ void k_scan(const int* __restrict__ deg, int* __restrict__ rowptr, int* __restrict__ cursor) {
    __shared__ int s_w[16];
    int t = threadIdx.x;
    int base = t * 20;
    int v[20]; int s = 0;
#pragma unroll
    for (int i = 0; i < 20; ++i) {
        int idx = base + i;
        v[i] = (idx < N_NODES) ? deg[idx] : 0;
        s += v[i];
    }
    int lane = t & 63, w = t >> 6;
    int inc = s;
#pragma unroll
    for (int off = 1; off < 64; off <<= 1) {
        int o = __shfl_up(inc, off);
        if (lane >= off) inc += o;
    }
    if (lane == 63) s_w[w] = inc;
    __syncthreads();
    if (w == 0 && lane < 16) {
        int x = s_w[lane];
        int xs = x;
#pragma unroll
        for (int off = 1; off < 16; off <<= 1) {
            int o = __shfl_up(xs, off);
            if (lane >= off) xs += o;
        }
        s_w[lane] = xs - x;
    }
    __syncthreads();
    int run = s_w[w] + (inc - s);
#pragma unroll
    for (int i = 0; i < 20; ++i) {
        int idx = base + i;
        if (idx < N_NODES) { rowptr[idx] = run; cursor[idx] = run; }
        else if (idx == N_NODES) rowptr[idx] = run;
        run += v[i];
    }
}

__global__ void k_fill(const int* __restrict__ ei, int* __restrict__ cursor, int* __restrict__ perm) {
    int e = blockIdx.x * 256 + threadIdx.x;
    if (e < N_EDGES) {
        int pos = atomicAdd(&cursor[ei[N_EDGES + e]], 1);
        perm[pos] = e;
    }
}

__global__ void k_node_init(const float* __restrict__ x, const float* __restrict__ W0,
                            const float* __restrict__ b0, float* __restrict__ hbuf) {
    int tid = threadIdx.x;
    int w = tid >> 6, j = tid & 63;
    int n = blockIdx.x * 4 + w;
    float acc = b0[j];
    const float* xr = x + n * IND;
#pragma unroll
    for (int i = 0; i < IND; ++i) acc = fmaf(xr[i], W0[i * 64 + j], acc);
    hbuf[n * 64 + j] = fmaxf(acc, 0.0f);
}

__global__ void k_edge_feat(const float* __restrict__ ea, const float* __restrict__ We1,
                            const float* __restrict__ be1, float* __restrict__ re) {
    int tid = threadIdx.x;
    int w = tid >> 6, k = tid & 63;
    int e = blockIdx.x * 4 + w;
    if (e >= N_EDGES) return;
    float acc = be1[k];
    const float* er = ea + e * 6;
#pragma unroll
    for (int i = 0; i < 6; ++i) acc = fmaf(er[i], We1[i * 64 + k], acc);
    re[e * 64 + k] = fmaxf(acc, 0.0f);
}

// msg[e,o] = sum_h v[e,h] * (sum_k re[e,k]*W[h,k,o])  + sum_h v[e,h]*be2[h,o]
// re packed to bf16 A-fragments ONCE; per slab: 8 MFMA (ew tile) + 16 fmac (rank-1 v apply).
__launch_bounds__(256, 3)
__global__ void k_msg_mfma(const float* __restrict__ hbuf, const float* __restrict__ reb,
                           const short* __restrict__ We2b, const int* __restrict__ ei,
                           float* __restrict__ msg) {
    __shared__ float s_v[64][64];    // [h][e]
    int tid = threadIdx.x;
    int eb = blockIdx.x * 64;
    int lane = tid & 63;
    int w = tid >> 6;
    int l15 = lane & 15, lhi = lane >> 4;

    // stage s_v transposed
    {
        int se = tid >> 2;
        int sh = tid & 3;
        int ge = eb + se;
        const float* rowp = (ge < N_EDGES) ? (hbuf + (size_t)ei[ge] * 64) : (const float*)0;
#pragma unroll
        for (int rr4 = 0; rr4 < 4; ++rr4) {
            int hb = rr4 * 16 + sh * 4;
            float4 vv = rowp ? *(const float4*)(rowp + hb) : make_float4(0.f, 0.f, 0.f, 0.f);
            s_v[hb + 0][se] = vv.x; s_v[hb + 1][se] = vv.y;
            s_v[hb + 2][se] = vv.z; s_v[hb + 3][se] = vv.w;
        }
    }

    // pack re A-fragments once (global reads, no LDS dep)
    union U { int4 i4; bf16x8 v; };
    U a_re[4][2];
#pragma unroll
    for (int m = 0; m < 4; ++m) {
        int ge = eb + m * 16 + l15;
        if (ge < N_EDGES) {
            const float* rp = reb + (size_t)ge * 64 + lhi * 8;
            float4 x0 = *(const float4*)(rp);
            float4 x1 = *(const float4*)(rp + 4);
            float4 y0 = *(const float4*)(rp + 32);
            float4 y1 = *(const float4*)(rp + 36);
            a_re[m][0].i4 = make_int4(pk2(x0.x, x0.y), pk2(x0.z, x0.w), pk2(x1.x, x1.y), pk2(x1.z, x1.w));
            a_re[m][1].i4 = make_int4(pk2(y0.x, y0.y), pk2(y0.z, y0.w), pk2(y1.x, y1.y), pk2(y1.z, y1.w));
        } else {
            a_re[m][0].i4 = make_int4(0, 0, 0, 0);
            a_re[m][1].i4 = make_int4(0, 0, 0, 0);
        }
    }
    __syncthreads();

    // pack v A-fragments for the bias slab (once)
    U a_v[4][2];
#pragma unroll
    for (int m = 0; m < 4; ++m) {
        int e = m * 16 + l15;
#pragma unroll
        for (int c = 0; c < 2; ++c) {
            int kb = c * 32 + lhi * 8;
            a_v[m][c].i4 = make_int4(
                pk2(s_v[kb + 0][e], s_v[kb + 1][e]),
                pk2(s_v[kb + 2][e], s_v[kb + 3][e]),
                pk2(s_v[kb + 4][e], s_v[kb + 5][e]),
                pk2(s_v[kb + 6][e], s_v[kb + 7][e]));
        }
    }

    const int4* bp0 = (const int4*)We2b + (w * 128 + lane);
    const int4* bp1 = bp0 + 64;
    int4 b0 = bp0[0], b1 = bp1[0];
    const f32x4 zero4 = {0.f, 0.f, 0.f, 0.f};
    f32x4 macc[4];
#pragma unroll
    for (int m = 0; m < 4; ++m) macc[m] = zero4;

    for (int h = 0; h < 64; ++h) {
        int4 nb0 = bp0[(h + 1) * 512];
        int4 nb1 = bp1[(h + 1) * 512];
        float4 v4[4];
#pragma unroll
        for (int m = 0; m < 4; ++m)
            v4[m] = *(const float4*)&s_v[h][m * 16 + lhi * 4];
        U bb0, bb1; bb0.i4 = b0; bb1.i4 = b1;
#pragma unroll
        for (int m = 0; m < 4; ++m) {
            f32x4 t = __builtin_amdgcn_mfma_f32_16x16x32_bf16(a_re[m][0].v, bb0.v, zero4, 0, 0, 0);
            t = __builtin_amdgcn_mfma_f32_16x16x32_bf16(a_re[m][1].v, bb1.v, t, 0, 0, 0);
            macc[m][0] = fmaf(v4[m].x, t[0], macc[m][0]);
            macc[m][1] = fmaf(v4[m].y, t[1], macc[m][1]);
            macc[m][2] = fmaf(v4[m].z, t[2], macc[m][2]);
            macc[m][3] = fmaf(v4[m].w, t[3], macc[m][3]);
        }
        b0 = nb0; b1 = nb1;
    }
    // bias slab (b0/b1 now hold slab 64): msg += v @ be2
    {
        U bb0, bb1; bb0.i4 = b0; bb1.i4 = b1;
#pragma unroll
        for (int m = 0; m < 4; ++m) {
            macc[m] = __builtin_amdgcn_mfma_f32_16x16x32_bf16(a_v[m][0].v, bb0.v, macc[m], 0, 0, 0);
            macc[m] = __builtin_amdgcn_mfma_f32_16x16x32_bf16(a_v[m][1].v, bb1.v, macc[m], 0, 0, 0);
        }
    }
    int o = w * 16 + l15;
#pragma unroll
    for (int m = 0; m < 4; ++m) {
#pragma unroll
        for (int r = 0; r < 4; ++r) {
            int el = m * 16 + lhi * 4 + r;
            int ge = eb + el;
            if (ge < N_EDGES) msg[(size_t)ge * 64 + o] = macc[m][r];
        }
    }
}

// MFMA node update: conv + GRU with split-bf16 weights (3-term MFMA ~ fp32 accuracy).
// 64 nodes / block. Wave w owns output cols w*16..w*16+15.
__launch_bounds__(256, 2)
__global__ void k_node_update(float* __restrict__ hbuf, const float* __restrict__ msg,
                              const int* __restrict__ rowptr, const int* __restrict__ perm,
                              const short* __restrict__ WB1h, const short* __restrict__ WB1l,
                              const short* __restrict__ WB2h, const short* __restrict__ WB2l,
                              const float* __restrict__ bconv, const float* __restrict__ bih,
                              const float* __restrict__ bhh) {
    __shared__ short s_hh[64][72];
    __shared__ short s_hl[64][72];
    __shared__ short s_mh[64][72];
    __shared__ short s_ml[64][72];
    __shared__ float s_agg[64][68];
    int tid = threadIdx.x;
    int nbase = blockIdx.x * 64;
    int lane = tid & 63, w = tid >> 6;
    int l15 = lane & 15, lhi = lane >> 4;

    // ---- stage h (split hi/lo) + gather agg (+bconv) ----
    {
        int nt = tid >> 2, q = tid & 3;
        int n = nbase + nt;
        bool valid = n < N_NODES;
#pragma unroll
        for (int c4 = 0; c4 < 4; ++c4) {
            int col = q * 16 + c4 * 4;
            float4 v = valid ? *(const float4*)&hbuf[(size_t)n * 64 + col]
                             : make_float4(0.f, 0.f, 0.f, 0.f);
            unsigned h01 = pk2(v.x, v.y), h23 = pk2(v.z, v.w);
            float f0 = __uint_as_float(h01 << 16);
            float f1 = __uint_as_float(h01 & 0xffff0000u);
            float f2 = __uint_as_float(h23 << 16);
            float f3 = __uint_as_float(h23 & 0xffff0000u);
            unsigned l01 = pk2(v.x - f0, v.y - f1), l23 = pk2(v.z - f2, v.w - f3);
            *(unsigned*)&s_hh[nt][col]     = h01;
            *(unsigned*)&s_hh[nt][col + 2] = h23;
            *(unsigned*)&s_hl[nt][col]     = l01;
            *(unsigned*)&s_hl[nt][col + 2] = l23;
        }
        float4 aggv[4];
#pragma unroll
        for (int c4 = 0; c4 < 4; ++c4)
            aggv[c4] = valid ? *(const float4*)&bconv[q * 16 + c4 * 4]
                             : make_float4(0.f, 0.f, 0.f, 0.f);
        if (valid) {
            int rs = rowptr[n], rend = rowptr[n + 1];
            for (int qq = rs; qq < rend; ++qq) {
                const float* mrow = msg + (size_t)perm[qq] * 64 + q * 16;
#pragma unroll
                for (int c4 = 0; c4 < 4; ++c4) {
                    float4 mv = *(const float4*)&mrow[c4 * 4];
                    aggv[c4].x += mv.x; aggv[c4].y += mv.y;
                    aggv[c4].z += mv.z; aggv[c4].w += mv.w;
                }
            }
        }
#pragma unroll
        for (int c4 = 0; c4 < 4; ++c4)
            *(float4*)&s_agg[nt][q * 16 + c4 * 4] = aggv[c4];
    }
    __syncthreads();

    union U { int4 i4; bf16x8 v; };
    // A fragments of h
    U ah[4][2], al[4][2];
#pragma unroll
    for (int m = 0; m < 4; ++m)
#pragma unroll
        for (int c = 0; c < 2; ++c) {
            ah[m][c].i4 = *(const int4*)&s_hh[m * 16 + l15][c * 32 + lhi * 8];
            al[m][c].i4 = *(const int4*)&s_hl[m * 16 + l15][c * 32 + lhi * 8];
        }

    const int4* B1h = (const int4*)WB1h;
    const int4* B1l = (const int4*)WB1l;
    const int4* B2h = (const int4*)WB2h;
    const int4* B2l = (const int4*)WB2l;

    f32x4 C0[4], G[3][4], I[3][4];

    // ---- pass 0: conv (cols w*16..w*16+15) ----
    {
        int ot = w;
        U bh0, bh1, bl0, bl1;
        bh0.i4 = B1h[(ot * 2 + 0) * 64 + lane];
        bh1.i4 = B1h[(ot * 2 + 1) * 64 + lane];
        bl0.i4 = B1l[(ot * 2 + 0) * 64 + lane];
        bl1.i4 = B1l[(ot * 2 + 1) * 64 + lane];
#pragma unroll
        for (int m = 0; m < 4; ++m) {
            f32x4 c;
#pragma unroll
            for (int r = 0; r < 4; ++r) c[r] = s_agg[m * 16 + lhi * 4 + r][w * 16 + l15];  // FIXED col
            c = __builtin_amdgcn_mfma_f32_16x16x32_bf16(ah[m][0].v, bh0.v, c, 0, 0, 0);
            c = __builtin_amdgcn_mfma_f32_16x16x32_bf16(ah[m][1].v, bh1.v, c, 0, 0, 0);
            c = __builtin_amdgcn_mfma_f32_16x16x32_bf16(al[m][0].v, bh0.v, c, 0, 0, 0);
            c = __builtin_amdgcn_mfma_f32_16x16x32_bf16(al[m][1].v, bh1.v, c, 0, 0, 0);
            c = __builtin_amdgcn_mfma_f32_16x16x32_bf16(ah[m][0].v, bl0.v, c, 0, 0, 0);
            c = __builtin_amdgcn_mfma_f32_16x16x32_bf16(ah[m][1].v, bl1.v, c, 0, 0, 0);
            C0[m] = c;
        }
    }
    // m = relu(conv) -> split hi/lo into LDS
#pragma unroll
    for (int m = 0; m < 4; ++m)
#pragma unroll
        for (int r = 0; r < 4; ++r) {
            float mv = fmaxf(C0[m][r], 0.0f);
            int row = m * 16 + lhi * 4 + r, col = w * 16 + l15;
            unsigned hs = bf1(mv);
            float lof = mv - __uint_as_float(hs << 16);
            s_mh[row][col] = (short)hs;
            s_ml[row][col] = (short)bf1(lof);
        }
    // ---- passes 1..3: gh gates ----
#pragma unroll
    for (int p = 1; p < 4; ++p) {
        int ot = p * 4 + w;
        U bh0, bh1, bl0, bl1;
        bh0.i4 = B1h[(ot * 2 + 0) * 64 + lane];
        bh1.i4 = B1h[(ot * 2 + 1) * 64 + lane];
        bl0.i4 = B1l[(ot * 2 + 0) * 64 + lane];
        bl1.i4 = B1l[(ot * 2 + 1) * 64 + lane];
        float bv = bhh[(p - 1) * 64 + w * 16 + l15];
#pragma unroll
        for (int m = 0; m < 4; ++m) {
            f32x4 c = {bv, bv, bv, bv};
            c = __builtin_amdgcn_mfma_f32_16x16x32_bf16(ah[m][0].v, bh0.v, c, 0, 0, 0);
            c = __builtin_amdgcn_mfma_f32_16x16x32_bf16(ah[m][1].v, bh1.v, c, 0, 0, 0);
            c = __builtin_amdgcn_mfma_f32_16x16x32_bf16(al[m][0].v, bh0.v, c, 0, 0, 0);
            c = __builtin_amdgcn_mfma_f32_16x16x32_bf16(al[m][1].v, bh1.v, c, 0, 0, 0);
            c = __builtin_amdgcn_mfma_f32_16x16x32_bf16(ah[m][0].v, bl0.v, c, 0, 0, 0);
            c = __builtin_amdgcn_mfma_f32_16x16x32_bf16(ah[m][1].v, bl1.v, c, 0, 0, 0);
            G[p - 1][m] = c;
        }
    }
    __syncthreads();
    // A fragments of m
    U mh[4][2], ml[4][2];
#pragma unroll
    for (int m = 0; m < 4; ++m)
#pragma unroll
        for (int c = 0; c < 2; ++c) {
            mh[m][c].i4 = *(const int4*)&s_mh[m * 16 + l15][c * 32 + lhi * 8];
            ml[m][c].i4 = *(const int4*)&s_ml[m * 16 + l15][c * 32 + lhi * 8];
        }
    // ---- gi passes ----
#pragma unroll
    for (int p = 0; p < 3; ++p) {
        int ot = p * 4 + w;
        U bh0, bh1, bl0, bl1;
        bh0.i4 = B2h[(ot * 2 + 0) * 64 + lane];
        bh1.i4 = B2h[(ot * 2 + 1) * 64 + lane];
        bl0.i4 = B2l[(ot * 2 + 0) * 64 + lane];
        bl1.i4 = B2l[(ot * 2 + 1) * 64 + lane];
        float bv = bih[p * 64 + w * 16 + l15];
#pragma unroll
        for (int m = 0; m < 4; ++m) {
            f32x4 c = {bv, bv, bv, bv};
            c = __builtin_amdgcn_mfma_f32_16x16x32_bf16(mh[m][0].v, bh0.v, c, 0, 0, 0);
            c = __builtin_amdgcn_mfma_f32_16x16x32_bf16(mh[m][1].v, bh1.v, c, 0, 0, 0);
            c = __builtin_amdgcn_mfma_f32_16x16x32_bf16(ml[m][0].v, bh0.v, c, 0, 0, 0);
            c = __builtin_amdgcn_mfma_f32_16x16x32_bf16(ml[m][1].v, bh1.v, c, 0, 0, 0);
            c = __builtin_amdgcn_mfma_f32_16x16x32_bf16(mh[m][0].v, bl0.v, c, 0, 0, 0);
            c = __builtin_amdgcn_mfma_f32_16x16x32_bf16(mh[m][1].v, bl1.v, c, 0, 0, 0);
            I[p][m] = c;
        }
    }
    // ---- activations + h write ----
#pragma unroll
    for (int m = 0; m < 4; ++m)
#pragma unroll
        for (int r = 0; r < 4; ++r) {
            int row = m * 16 + lhi * 4 + r;
            int n = nbase + row;
            if (n < N_NODES) {
                int col = w * 16 + l15;
                float hold = __uint_as_float(((unsigned)(unsigned short)s_hh[row][col]) << 16)
                           + __uint_as_float(((unsigned)(unsigned short)s_hl[row][col]) << 16);
                float rg = sigmoidf_(I[0][m][r] + G[0][m][r]);
                float z  = sigmoidf_(I[1][m][r] + G[1][m][r]);
                float nn = tanhf_(I[2][m][r] + rg * G[2][m][r]);
                hbuf[(size_t)n * 64 + col] = (1.0f - z) * nn + z * hold;
            }
        }
}

// Set2Set LSTM step, one block (256 thr) per graph
__global__ void k_lstm(const float* __restrict__ q_star, float* __restrict__ qh, float* __restrict__ qc,
                       const float* __restrict__ l_wihT, const float* __restrict__ l_whhT,
                       const float* __restrict__ l_bih, const float* __restrict__ l_bhh) {
    __shared__ float s_qs[128];
    __shared__ float s_qh[64];
    __shared__ float s_g[256];
    int b = blockIdx.x;
    int j = threadIdx.x;
    if (j < 128) s_qs[j] = q_star[b * 128 + j];
    else if (j < 192) s_qh[j - 128] = qh[b * 64 + (j - 128)];
    __syncthreads();
    float g = l_bih[j] + l_bhh[j];
#pragma unroll 8
    for (int i = 0; i < 128; ++i) g = fmaf(s_qs[i], l_wihT[i * 256 + j], g);
#pragma unroll 8
    for (int i = 0; i < 64; ++i)  g = fmaf(s_qh[i], l_whhT[i * 256 + j], g);
    s_g[j] = g;
    __syncthreads();
    if (j < 64) {
        float ci = sigmoidf_(s_g[j]);
        float cf = sigmoidf_(s_g[64 + j]);
        float cg = tanhf_(s_g[128 + j]);
        float co = sigmoidf_(s_g[192 + j]);
        float c = cf * qc[b * 64 + j] + ci * cg;
        qc[b * 64 + j] = c;
        qh[b * 64 + j] = co * tanhf_(c);
    }
}

// per-graph online-softmax attention. 1 wave/graph.
__global__ void k_attention(const float* __restrict__ hbuf, const float* __restrict__ qh,
                            const int* __restrict__ offs, float* __restrict__ q_star) {
    int tid = threadIdx.x;
    int w = tid >> 6, lane = tid & 63;
    int b = blockIdx.x * 4 + w;
    int s = offs[b], e = offs[b + 1];
    float qv = qh[b * 64 + lane];
    float mx = -1e30f, l = 0.0f, racc = 0.0f;
    for (int n = s; n < e; ++n) {
        float xv = hbuf[n * 64 + lane];
        float prod = xv * qv;
#pragma unroll
        for (int off = 32; off > 0; off >>= 1) prod += __shfl_xor(prod, off);
        float mnew = fmaxf(mx, prod);
        float scale = __expf(mx - mnew);
        float wgt = __expf(prod - mnew);
        l = l * scale + wgt;
        racc = racc * scale + wgt * xv;
        mx = mnew;
    }
    float r = (e > s) ? (racc / l) : 0.0f;
    q_star[b * 128 + lane] = qv;
    q_star[b * 128 + 64 + lane] = r;
}

// readout MLP, 1 wave/graph
__global__ void k_readout(const float* __restrict__ q_star, const float* __restrict__ t,
                          const float* __restrict__ p, const float* __restrict__ W1,
                          const float* __restrict__ b1, const float* __restrict__ W2,
                          const float* __restrict__ b2, const float* __restrict__ W3,
                          const float* __restrict__ b3, float* __restrict__ y) {
    __shared__ float s_qs[4][128];
    __shared__ float s_y[4][64];
    int tid = threadIdx.x;
    int w = tid >> 6, j = tid & 63;
    int b = blockIdx.x * 4 + w;
    s_qs[w][j] = q_star[b * 128 + j];
    s_qs[w][64 + j] = q_star[b * 128 + 64 + j];
    __syncthreads();
    float acc = b1[j];
#pragma unroll 8
    for (int i = 0; i < 128; ++i) acc = fmaf(s_qs[w][i], W1[i * 64 + j], acc);
    acc = fmaf(t[b], W1[128 * 64 + j], acc);
    acc = fmaf(p[b], W1[129 * 64 + j], acc);
    acc = fmaxf(acc, 0.0f);
    s_y[w][j] = acc;
    __syncthreads();
    float acc2 = b2[j];
#pragma unroll 8
    for (int i = 0; i < 64; ++i) acc2 = fmaf(s_y[w][i], W2[i * 64 + j], acc2);
    acc2 = fmaxf(acc2, 0.0f);
    float part = acc2 * W3[j];
#pragma unroll
    for (int off = 32; off > 0; off >>= 1) part += __shfl_xor(part, off);
    if (j == 0) y[b] = part + b3[0];
}

extern "C" void kernel_launch(void* const* d_in, const int* in_sizes, int n_in,
                              void* d_out, int out_size, void* d_ws, size_t ws_size,
                              hipStream_t stream) {
    const float* x     = (const float*)d_in[0];
    const int*   ei    = (const int*)  d_in[1];
    const float* ea    = (const float*)d_in[2];
    const int*   batch = (const int*)  d_in[3];
    const float* t     = (const float*)d_in[4];
    const float* p     = (const float*)d_in[5];
    const float* W0    = (const float*)d_in[7];
    const float* b0    = (const float*)d_in[8];
    const float* We1   = (const float*)d_in[9];
    const float* be1   = (const float*)d_in[10];
    const float* We2   = (const float*)d_in[11];
    const float* be2   = (const float*)d_in[12];
    const float* Wroot = (const float*)d_in[13];
    const float* bconv = (const float*)d_in[14];
    const float* gwih  = (const float*)d_in[15];
    const float* gwhh  = (const float*)d_in[16];
    const float* gbih  = (const float*)d_in[17];
    const float* gbhh  = (const float*)d_in[18];
    const float* lwih  = (const float*)d_in[19];
    const float* lwhh  = (const float*)d_in[20];
    const float* lbih  = (const float*)d_in[21];
    const float* lbhh  = (const float*)d_in[22];
    const float* W1    = (const float*)d_in[23];
    const float* b1    = (const float*)d_in[24];
    const float* W2    = (const float*)d_in[25];
    const float* b2    = (const float*)d_in[26];
    const float* W3    = (const float*)d_in[27];
    const float* b3    = (const float*)d_in[28];
    float* y = (float*)d_out;

    char* ws = (char*)d_ws;
    size_t off = 0;
    auto alloc = [&](size_t nbytes) {
        void* ptr = (void*)(ws + off);
        off += align_up(nbytes, 256);
        return ptr;
    };
    float* hbuf   = (float*)alloc((size_t)N_NODES * 64 * 4);
    float* reb    = (float*)alloc((size_t)N_EDGES * 64 * 4);
    float* msg    = (float*)alloc((size_t)N_EDGES * 64 * 4);
    short* We2b   = (short*)alloc((size_t)65 * 4096 * 2);
    short* WB1h   = (short*)alloc(16384 * 2);
    short* WB1l   = (short*)alloc(16384 * 2);
    short* WB2h   = (short*)alloc(12288 * 2);
    short* WB2l   = (short*)alloc(12288 * 2);
    float* lwihT  = (float*)alloc(128 * 256 * 4);
    float* lwhhT  = (float*)alloc(64 * 256 * 4);
    float* qh     = (float*)alloc(NB * 64 * 4);
    float* qc     = (float*)alloc(NB * 64 * 4);
    float* qstar  = (float*)alloc(NB * 128 * 4);
    int*   offs   = (int*)  alloc((NB + 1) * 4);
    int*   deg    = (int*)  alloc(N_NODES * 4);
    int*   rowptr = (int*)  alloc((N_NODES + 1) * 4);
    int*   cursor = (int*)  alloc(N_NODES * 4);
    int*   perm   = (int*)  alloc(N_EDGES * 4);

    // ---- prep ----
    k_transpose<<<(256 * 128 + 255) / 256, 256, 0, stream>>>(lwih, lwihT, 256, 128);
    k_transpose<<<(256 * 64 + 255) / 256, 256, 0, stream>>>(lwhh, lwhhT, 256, 64);
    k_we2b<<<65 * 4096 / 256, 256, 0, stream>>>(We2, be2, We2b);
    k_wsplit<<<(28672 + 255) / 256, 256, 0, stream>>>(Wroot, gwhh, gwih, WB1h, WB1l, WB2h, WB2l);
    k_offsets<<<5, 256, 0, stream>>>(batch, offs);
    hipMemsetAsync(qh, 0, (size_t)(NB * 64 + NB * 64 + NB * 128) * 4, stream); // qh|qc|qstar contiguous
    hipMemsetAsync(deg, 0, (size_t)N_NODES * 4, stream);
    k_count<<<(N_EDGES + 255) / 256, 256, 0, stream>>>(ei, deg);
    k_scan<<<1, 1024, 0, stream>>>(deg, rowptr, cursor);
    k_fill<<<(N_EDGES + 255) / 256, 256, 0, stream>>>(ei, cursor, perm);

    // ---- encoder ----
    k_node_init<<<N_NODES / 4, 256, 0, stream>>>(x, W0, b0, hbuf);
    k_edge_feat<<<N_EDGES / 4, 256, 0, stream>>>(ea, We1, be1, reb);

    // ---- 4 message-passing + GRU iterations ----
    for (int it = 0; it < 4; ++it) {
        k_msg_mfma<<<(N_EDGES + 63) / 64, 256, 0, stream>>>(hbuf, reb, We2b, ei, msg);
        k_node_update<<<(N_NODES + 63) / 64, 256, 0, stream>>>(hbuf, msg, rowptr, perm,
                                                               WB1h, WB1l, WB2h, WB2l,
                                                               bconv, gbih, gbhh);
    }

    // ---- Set2Set, 3 steps ----
    for (int itr = 0; itr < 3; ++itr) {
        k_lstm<<<NB, 256, 0, stream>>>(qstar, qh, qc, lwihT, lwhhT, lbih, lbhh);
        k_attention<<<NB / 4, 256, 0, stream>>>(hbuf, qh, offs, qstar);
    }

    // ---- readout ----
    k_readout<<<NB / 4, 256, 0, stream>>>(qstar, t, p, W1, b1, W2, b2, W3, b3, y);
}

// Round 5
// 490.749 us; speedup vs baseline: 8.2646x; 1.0273x over previous
//
#include <hip/hip_runtime.h>
#include <math.h>

#define N_NODES 20000
#define N_EDGES 50000
#define NB      1024
#define IND     32
#define HDIM    64

typedef __attribute__((ext_vector_type(8))) short bf16x8;
typedef __attribute__((ext_vector_type(4))) float f32x4;

static inline size_t align_up(size_t x, size_t a) { return (x + a - 1) & ~(a - 1); }

__device__ __forceinline__ float sigmoidf_(float x) {
    return 1.0f / (1.0f + __expf(-x));
}
__device__ __forceinline__ float tanhf_(float x) {
    float xc = fminf(fmaxf(x, -15.0f), 15.0f);
    float e = __expf(2.0f * xc);
    return (e - 1.0f) / (e + 1.0f);
}
// pack two fp32 -> dword of two bf16 (round-half-up)
__device__ __forceinline__ unsigned pk2(float p0, float p1) {
    unsigned u0 = __float_as_uint(p0) + 0x8000u;
    unsigned u1 = __float_as_uint(p1) + 0x8000u;
    return __builtin_amdgcn_perm(u1, u0, 0x07060302u);
}
__device__ __forceinline__ unsigned bf1(float v) {
    return (__float_as_uint(v) + 0x8000u) >> 16;
}

// out[c*R + r] = in[r*C + c]
__global__ void k_transpose(const float* __restrict__ in, float* __restrict__ out, int R, int C) {
    int idx = blockIdx.x * 256 + threadIdx.x;
    if (idx >= R * C) return;
    int r = idx / C, c = idx - r * C;
    out[c * R + r] = in[idx];
}

// We2b: 65 slabs of 4096 bf16, fragment-ordered for 16x16x32 MFMA B-operand.
// slab s<64: B_s[k][o] = We2[k*4096 + s*64 + o]; slab 64: B[k][o] = be2[k*64+o].
__global__ void k_we2b(const float* __restrict__ We2, const float* __restrict__ be2,
                       short* __restrict__ We2b) {
    int idx = blockIdx.x * 256 + threadIdx.x;     // 0 .. 65*4096-1
    int s = idx >> 12;
    int col = idx & 4095;
    int k = col >> 6, o = col & 63;
    float val = (s < 64) ? We2[k * 4096 + s * 64 + o] : be2[k * 64 + o];
    int dst = s * 4096 + (((o >> 4) * 128 + (k >> 5) * 64 + ((k >> 3) & 3) * 16 + (o & 15)) << 3) + (k & 7);
    We2b[dst] = (short)bf1(val);
}

// split-bf16 fragment-ordered weights for node update.
// WB1 (16384 shorts): B1[k][o], o<64: Wroot[k][o]; o in [64,256): whh[(o-64)][k]
// WB2 (12288 shorts): B2[k][o] = wih[o][k], o in [0,192)
// linear idx = ((otile*2 + c)*64 + lane)*8 + j ; k = c*32 + (lane>>4)*8 + j ; o = otile*16 + (lane&15)
__global__ void k_wsplit(const float* __restrict__ Wroot, const float* __restrict__ gwhh,
                         const float* __restrict__ gwih,
                         short* __restrict__ WB1h, short* __restrict__ WB1l,
                         short* __restrict__ WB2h, short* __restrict__ WB2l) {
    int idx = blockIdx.x * 256 + threadIdx.x;   // 0..28671
    if (idx >= 28672) return;
    bool b1 = idx < 16384;
    int li = b1 ? idx : idx - 16384;
    int j = li & 7, lane = (li >> 3) & 63, c = (li >> 9) & 1, otile = li >> 10;
    int k = c * 32 + (lane >> 4) * 8 + j;
    int o = otile * 16 + (lane & 15);
    float val;
    if (b1) val = (o < 64) ? Wroot[k * 64 + o] : gwhh[(o - 64) * 64 + k];
    else    val = gwih[o * 64 + k];
    unsigned hs = bf1(val);
    float lo = val - __uint_as_float(hs << 16);
    unsigned ls = bf1(lo);
    if (b1) { WB1h[li] = (short)hs; WB1l[li] = (short)ls; }
    else    { WB2h[li] = (short)hs; WB2l[li] = (short)ls; }
}

// offs[i] = lower_bound(batch, i)
__global__ void k_offsets(const int* __restrict__ batch, int* __restrict__ offs) {
    int i = blockIdx.x * 256 + threadIdx.x;
    if (i > NB) return;
    int lo = 0, hi = N_NODES;
    while (lo < hi) { int mid = (lo + hi) >> 1; if (batch[mid] < i) lo = mid + 1; else hi = mid; }
    offs[i] = lo;
}

// ---- CSR build ----
__global__ void k_count(const int* __restrict__ ei, int* __restrict__ deg) {
    int e = blockIdx.x * 256 + threadIdx.x;
    if (e < N_EDGES) atomicAdd(&deg[ei[N_EDGES + e]], 1);
}

__global__ void k_scan(const int* __restrict__ deg, int* __restrict__ rowptr, int* __restrict__ cursor) {
    __shared__ int s_w[16];
    int t = threadIdx.x;
    int base = t * 20;
    int v[20]; int s = 0;
#pragma unroll
    for (int i = 0; i < 20; ++i) {
        int idx = base + i;
        v[i] = (idx < N_NODES) ? deg[idx] : 0;
        s += v[i];
    }
    int lane = t & 63, w = t >> 6;
    int inc = s;
#pragma unroll
    for (int off = 1; off < 64; off <<= 1) {
        int o = __shfl_up(inc, off);
        if (lane >= off) inc += o;
    }
    if (lane == 63) s_w[w] = inc;
    __syncthreads();
    if (w == 0 && lane < 16) {
        int x = s_w[lane];
        int xs = x;
#pragma unroll
        for (int off = 1; off < 16; off <<= 1) {
            int o = __shfl_up(xs, off);
            if (lane >= off) xs += o;
        }
        s_w[lane] = xs - x;
    }
    __syncthreads();
    int run = s_w[w] + (inc - s);
#pragma unroll
    for (int i = 0; i < 20; ++i) {
        int idx = base + i;
        if (idx < N_NODES) { rowptr[idx] = run; cursor[idx] = run; }
        else if (idx == N_NODES) rowptr[idx] = run;
        run += v[i];
    }
}

__global__ void k_fill(const int* __restrict__ ei, int* __restrict__ cursor, int* __restrict__ perm) {
    int e = blockIdx.x * 256 + threadIdx.x;
    if (e < N_EDGES) {
        int pos = atomicAdd(&cursor[ei[N_EDGES + e]], 1);
        perm[pos] = e;
    }
}

__global__ void k_node_init(const float* __restrict__ x, const float* __restrict__ W0,
                            const float* __restrict__ b0, float* __restrict__ hbuf) {
    int tid = threadIdx.x;
    int w = tid >> 6, j = tid & 63;
    int n = blockIdx.x * 4 + w;
    float acc = b0[j];
    const float* xr = x + n * IND;
#pragma unroll
    for (int i = 0; i < IND; ++i) acc = fmaf(xr[i], W0[i * 64 + j], acc);
    hbuf[n * 64 + j] = fmaxf(acc, 0.0f);
}

__global__ void k_edge_feat(const float* __restrict__ ea, const float* __restrict__ We1,
                            const float* __restrict__ be1, float* __restrict__ re) {
    int tid = threadIdx.x;
    int w = tid >> 6, k = tid & 63;
    int e = blockIdx.x * 4 + w;
    if (e >= N_EDGES) return;
    float acc = be1[k];
    const float* er = ea + e * 6;
#pragma unroll
    for (int i = 0; i < 6; ++i) acc = fmaf(er[i], We1[i * 64 + k], acc);
    re[e * 64 + k] = fmaxf(acc, 0.0f);
}

// msg[e,o] = sum_h v[e,h] * (sum_k re[e,k]*W[h,k,o])  + sum_h v[e,h]*be2[h,o]
// K-loop: depth-4 register prefetch of B slabs (rotating 4 sets, unroll-4), depth-1
// LDS prefetch of v. Per slab: 8 MFMA + 16 fmac, no per-slab latency exposure.
__launch_bounds__(256, 3)
__global__ void k_msg_mfma(const float* __restrict__ hbuf, const float* __restrict__ reb,
                           const short* __restrict__ We2b, const int* __restrict__ ei,
                           float* __restrict__ msg) {
    __shared__ float s_v[64][64];    // [h][e]
    int tid = threadIdx.x;
    int eb = blockIdx.x * 64;
    int lane = tid & 63;
    int w = tid >> 6;
    int l15 = lane & 15, lhi = lane >> 4;

    // stage s_v transposed
    {
        int se = tid >> 2;
        int sh = tid & 3;
        int ge = eb + se;
        const float* rowp = (ge < N_EDGES) ? (hbuf + (size_t)ei[ge] * 64) : (const float*)0;
#pragma unroll
        for (int rr4 = 0; rr4 < 4; ++rr4) {
            int hb = rr4 * 16 + sh * 4;
            float4 vv = rowp ? *(const float4*)(rowp + hb) : make_float4(0.f, 0.f, 0.f, 0.f);
            s_v[hb + 0][se] = vv.x; s_v[hb + 1][se] = vv.y;
            s_v[hb + 2][se] = vv.z; s_v[hb + 3][se] = vv.w;
        }
    }

    // pack re A-fragments once (global reads, no LDS dep)
    union U { int4 i4; bf16x8 v; };
    U a_re[4][2];
#pragma unroll
    for (int m = 0; m < 4; ++m) {
        int ge = eb + m * 16 + l15;
        if (ge < N_EDGES) {
            const float* rp = reb + (size_t)ge * 64 + lhi * 8;
            float4 x0 = *(const float4*)(rp);
            float4 x1 = *(const float4*)(rp + 4);
            float4 y0 = *(const float4*)(rp + 32);
            float4 y1 = *(const float4*)(rp + 36);
            a_re[m][0].i4 = make_int4(pk2(x0.x, x0.y), pk2(x0.z, x0.w), pk2(x1.x, x1.y), pk2(x1.z, x1.w));
            a_re[m][1].i4 = make_int4(pk2(y0.x, y0.y), pk2(y0.z, y0.w), pk2(y1.x, y1.y), pk2(y1.z, y1.w));
        } else {
            a_re[m][0].i4 = make_int4(0, 0, 0, 0);
            a_re[m][1].i4 = make_int4(0, 0, 0, 0);
        }
    }

    // B prefetch: 4 rotating register sets, depth 4 (slab s loaded 4 slabs before use)
    const int4* bp0 = (const int4*)We2b + (w * 128 + lane);   // slab stride = 512 int4
    const int4* bp1 = bp0 + 64;
    int4 Sc0[4], Sc1[4];
#pragma unroll
    for (int j = 0; j < 4; ++j) {
        Sc0[j] = bp0[j * 512];
        Sc1[j] = bp1[j * 512];
    }

    __syncthreads();

    const f32x4 zero4 = {0.f, 0.f, 0.f, 0.f};
    f32x4 macc[4];
#pragma unroll
    for (int m = 0; m < 4; ++m) macc[m] = zero4;

    // v prefetch depth 1
    float4 vv[4], vn[4];
#pragma unroll
    for (int m = 0; m < 4; ++m) vv[m] = *(const float4*)&s_v[0][m * 16 + lhi * 4];

    for (int g = 0; g < 16; ++g) {
#pragma unroll
        for (int j = 0; j < 4; ++j) {
            int s = g * 4 + j;
            int snext = (s < 63) ? (s + 1) : 63;
#pragma unroll
            for (int m = 0; m < 4; ++m)
                vn[m] = *(const float4*)&s_v[snext][m * 16 + lhi * 4];
            U bb0, bb1; bb0.i4 = Sc0[j]; bb1.i4 = Sc1[j];
#pragma unroll
            for (int m = 0; m < 4; ++m) {
                f32x4 t = __builtin_amdgcn_mfma_f32_16x16x32_bf16(a_re[m][0].v, bb0.v, zero4, 0, 0, 0);
                t = __builtin_amdgcn_mfma_f32_16x16x32_bf16(a_re[m][1].v, bb1.v, t, 0, 0, 0);
                macc[m][0] = fmaf(vv[m].x, t[0], macc[m][0]);
                macc[m][1] = fmaf(vv[m].y, t[1], macc[m][1]);
                macc[m][2] = fmaf(vv[m].z, t[2], macc[m][2]);
                macc[m][3] = fmaf(vv[m].w, t[3], macc[m][3]);
            }
            int sload = (s + 4 <= 64) ? (s + 4) : 64;
            Sc0[j] = bp0[sload * 512];
            Sc1[j] = bp1[sload * 512];
#pragma unroll
            for (int m = 0; m < 4; ++m) vv[m] = vn[m];
        }
    }

    // bias slab (set 0 holds slab 64): msg += v @ be2 ; a_v built here (regs free now)
    {
        U bb0, bb1; bb0.i4 = Sc0[0]; bb1.i4 = Sc1[0];
#pragma unroll
        for (int m = 0; m < 4; ++m) {
            int e = m * 16 + l15;
            U a0, a1;
            a0.i4 = make_int4(
                pk2(s_v[lhi * 8 + 0][e], s_v[lhi * 8 + 1][e]),
                pk2(s_v[lhi * 8 + 2][e], s_v[lhi * 8 + 3][e]),
                pk2(s_v[lhi * 8 + 4][e], s_v[lhi * 8 + 5][e]),
                pk2(s_v[lhi * 8 + 6][e], s_v[lhi * 8 + 7][e]));
            a1.i4 = make_int4(
                pk2(s_v[32 + lhi * 8 + 0][e], s_v[32 + lhi * 8 + 1][e]),
                pk2(s_v[32 + lhi * 8 + 2][e], s_v[32 + lhi * 8 + 3][e]),
                pk2(s_v[32 + lhi * 8 + 4][e], s_v[32 + lhi * 8 + 5][e]),
                pk2(s_v[32 + lhi * 8 + 6][e], s_v[32 + lhi * 8 + 7][e]));
            macc[m] = __builtin_amdgcn_mfma_f32_16x16x32_bf16(a0.v, bb0.v, macc[m], 0, 0, 0);
            macc[m] = __builtin_amdgcn_mfma_f32_16x16x32_bf16(a1.v, bb1.v, macc[m], 0, 0, 0);
        }
    }
    int o = w * 16 + l15;
#pragma unroll
    for (int m = 0; m < 4; ++m) {
#pragma unroll
        for (int r = 0; r < 4; ++r) {
            int el = m * 16 + lhi * 4 + r;
            int ge = eb + el;
            if (ge < N_EDGES) msg[(size_t)ge * 64 + o] = macc[m][r];
        }
    }
}

// MFMA node update: conv + GRU with split-bf16 weights (3-term MFMA ~ fp32 accuracy).
// 64 nodes / block. Wave w owns output cols w*16..w*16+15.
__launch_bounds__(256, 2)
__global__ void k_node_update(float* __restrict__ hbuf, const float* __restrict__ msg,
                              const int* __restrict__ rowptr, const int* __restrict__ perm,
                              const short* __restrict__ WB1h, const short* __restrict__ WB1l,
                              const short* __restrict__ WB2h, const short* __restrict__ WB2l,
                              const float* __restrict__ bconv, const float* __restrict__ bih,
                              const float* __restrict__ bhh) {
    __shared__ short s_hh[64][72];
    __shared__ short s_hl[64][72];
    __shared__ short s_mh[64][72];
    __shared__ short s_ml[64][72];
    __shared__ float s_agg[64][68];
    int tid = threadIdx.x;
    int nbase = blockIdx.x * 64;
    int lane = tid & 63, w = tid >> 6;
    int l15 = lane & 15, lhi = lane >> 4;

    // ---- stage h (split hi/lo) + gather agg (+bconv) ----
    {
        int nt = tid >> 2, q = tid & 3;
        int n = nbase + nt;
        bool valid = n < N_NODES;
#pragma unroll
        for (int c4 = 0; c4 < 4; ++c4) {
            int col = q * 16 + c4 * 4;
            float4 v = valid ? *(const float4*)&hbuf[(size_t)n * 64 + col]
                             : make_float4(0.f, 0.f, 0.f, 0.f);
            unsigned h01 = pk2(v.x, v.y), h23 = pk2(v.z, v.w);
            float f0 = __uint_as_float(h01 << 16);
            float f1 = __uint_as_float(h01 & 0xffff0000u);
            float f2 = __uint_as_float(h23 << 16);
            float f3 = __uint_as_float(h23 & 0xffff0000u);
            unsigned l01 = pk2(v.x - f0, v.y - f1), l23 = pk2(v.z - f2, v.w - f3);
            *(unsigned*)&s_hh[nt][col]     = h01;
            *(unsigned*)&s_hh[nt][col + 2] = h23;
            *(unsigned*)&s_hl[nt][col]     = l01;
            *(unsigned*)&s_hl[nt][col + 2] = l23;
        }
        float4 aggv[4];
#pragma unroll
        for (int c4 = 0; c4 < 4; ++c4)
            aggv[c4] = valid ? *(const float4*)&bconv[q * 16 + c4 * 4]
                             : make_float4(0.f, 0.f, 0.f, 0.f);
        if (valid) {
            int rs = rowptr[n], rend = rowptr[n + 1];
            for (int qq = rs; qq < rend; ++qq) {
                const float* mrow = msg + (size_t)perm[qq] * 64 + q * 16;
#pragma unroll
                for (int c4 = 0; c4 < 4; ++c4) {
                    float4 mv = *(const float4*)&mrow[c4 * 4];
                    aggv[c4].x += mv.x; aggv[c4].y += mv.y;
                    aggv[c4].z += mv.z; aggv[c4].w += mv.w;
                }
            }
        }
#pragma unroll
        for (int c4 = 0; c4 < 4; ++c4)
            *(float4*)&s_agg[nt][q * 16 + c4 * 4] = aggv[c4];
    }
    __syncthreads();

    union U { int4 i4; bf16x8 v; };
    // A fragments of h
    U ah[4][2], al[4][2];
#pragma unroll
    for (int m = 0; m < 4; ++m)
#pragma unroll
        for (int c = 0; c < 2; ++c) {
            ah[m][c].i4 = *(const int4*)&s_hh[m * 16 + l15][c * 32 + lhi * 8];
            al[m][c].i4 = *(const int4*)&s_hl[m * 16 + l15][c * 32 + lhi * 8];
        }

    const int4* B1h = (const int4*)WB1h;
    const int4* B1l = (const int4*)WB1l;
    const int4* B2h = (const int4*)WB2h;
    const int4* B2l = (const int4*)WB2l;

    f32x4 C0[4], G[3][4], I[3][4];

    // ---- pass 0: conv (cols w*16..w*16+15) ----
    {
        int ot = w;
        U bh0, bh1, bl0, bl1;
        bh0.i4 = B1h[(ot * 2 + 0) * 64 + lane];
        bh1.i4 = B1h[(ot * 2 + 1) * 64 + lane];
        bl0.i4 = B1l[(ot * 2 + 0) * 64 + lane];
        bl1.i4 = B1l[(ot * 2 + 1) * 64 + lane];
#pragma unroll
        for (int m = 0; m < 4; ++m) {
            f32x4 c;
#pragma unroll
            for (int r = 0; r < 4; ++r) c[r] = s_agg[m * 16 + lhi * 4 + r][w * 16 + l15];
            c = __builtin_amdgcn_mfma_f32_16x16x32_bf16(ah[m][0].v, bh0.v, c, 0, 0, 0);
            c = __builtin_amdgcn_mfma_f32_16x16x32_bf16(ah[m][1].v, bh1.v, c, 0, 0, 0);
            c = __builtin_amdgcn_mfma_f32_16x16x32_bf16(al[m][0].v, bh0.v, c, 0, 0, 0);
            c = __builtin_amdgcn_mfma_f32_16x16x32_bf16(al[m][1].v, bh1.v, c, 0, 0, 0);
            c = __builtin_amdgcn_mfma_f32_16x16x32_bf16(ah[m][0].v, bl0.v, c, 0, 0, 0);
            c = __builtin_amdgcn_mfma_f32_16x16x32_bf16(ah[m][1].v, bl1.v, c, 0, 0, 0);
            C0[m] = c;
        }
    }
    // m = relu(conv) -> split hi/lo into LDS
#pragma unroll
    for (int m = 0; m < 4; ++m)
#pragma unroll
        for (int r = 0; r < 4; ++r) {
            float mv = fmaxf(C0[m][r], 0.0f);
            int row = m * 16 + lhi * 4 + r, col = w * 16 + l15;
            unsigned hs = bf1(mv);
            float lof = mv - __uint_as_float(hs << 16);
            s_mh[row][col] = (short)hs;
            s_ml[row][col] = (short)bf1(lof);
        }
    // ---- passes 1..3: gh gates ----
#pragma unroll
    for (int p = 1; p < 4; ++p) {
        int ot = p * 4 + w;
        U bh0, bh1, bl0, bl1;
        bh0.i4 = B1h[(ot * 2 + 0) * 64 + lane];
        bh1.i4 = B1h[(ot * 2 + 1) * 64 + lane];
        bl0.i4 = B1l[(ot * 2 + 0) * 64 + lane];
        bl1.i4 = B1l[(ot * 2 + 1) * 64 + lane];
        float bv = bhh[(p - 1) * 64 + w * 16 + l15];
#pragma unroll
        for (int m = 0; m < 4; ++m) {
            f32x4 c = {bv, bv, bv, bv};
            c = __builtin_amdgcn_mfma_f32_16x16x32_bf16(ah[m][0].v, bh0.v, c, 0, 0, 0);
            c = __builtin_amdgcn_mfma_f32_16x16x32_bf16(ah[m][1].v, bh1.v, c, 0, 0, 0);
            c = __builtin_amdgcn_mfma_f32_16x16x32_bf16(al[m][0].v, bh0.v, c, 0, 0, 0);
            c = __builtin_amdgcn_mfma_f32_16x16x32_bf16(al[m][1].v, bh1.v, c, 0, 0, 0);
            c = __builtin_amdgcn_mfma_f32_16x16x32_bf16(ah[m][0].v, bl0.v, c, 0, 0, 0);
            c = __builtin_amdgcn_mfma_f32_16x16x32_bf16(ah[m][1].v, bl1.v, c, 0, 0, 0);
            G[p - 1][m] = c;
        }
    }
    __syncthreads();
    // A fragments of m
    U mh[4][2], ml[4][2];
#pragma unroll
    for (int m = 0; m < 4; ++m)
#pragma unroll
        for (int c = 0; c < 2; ++c) {
            mh[m][c].i4 = *(const int4*)&s_mh[m * 16 + l15][c * 32 + lhi * 8];
            ml[m][c].i4 = *(const int4*)&s_ml[m * 16 + l15][c * 32 + lhi * 8];
        }
    // ---- gi passes ----
#pragma unroll
    for (int p = 0; p < 3; ++p) {
        int ot = p * 4 + w;
        U bh0, bh1, bl0, bl1;
        bh0.i4 = B2h[(ot * 2 + 0) * 64 + lane];
        bh1.i4 = B2h[(ot * 2 + 1) * 64 + lane];
        bl0.i4 = B2l[(ot * 2 + 0) * 64 + lane];
        bl1.i4 = B2l[(ot * 2 + 1) * 64 + lane];
        float bv = bih[p * 64 + w * 16 + l15];
#pragma unroll
        for (int m = 0; m < 4; ++m) {
            f32x4 c = {bv, bv, bv, bv};
            c = __builtin_amdgcn_mfma_f32_16x16x32_bf16(mh[m][0].v, bh0.v, c, 0, 0, 0);
            c = __builtin_amdgcn_mfma_f32_16x16x32_bf16(mh[m][1].v, bh1.v, c, 0, 0, 0);
            c = __builtin_amdgcn_mfma_f32_16x16x32_bf16(ml[m][0].v, bh0.v, c, 0, 0, 0);
            c = __builtin_amdgcn_mfma_f32_16x16x32_bf16(ml[m][1].v, bh1.v, c, 0, 0, 0);
            c = __builtin_amdgcn_mfma_f32_16x16x32_bf16(mh[m][0].v, bl0.v, c, 0, 0, 0);
            c = __builtin_amdgcn_mfma_f32_16x16x32_bf16(mh[m][1].v, bl1.v, c, 0, 0, 0);
            I[p][m] = c;
        }
    }
    // ---- activations + h write ----
#pragma unroll
    for (int m = 0; m < 4; ++m)
#pragma unroll
        for (int r = 0; r < 4; ++r) {
            int row = m * 16 + lhi * 4 + r;
            int n = nbase + row;
            if (n < N_NODES) {
                int col = w * 16 + l15;
                float hold = __uint_as_float(((unsigned)(unsigned short)s_hh[row][col]) << 16)
                           + __uint_as_float(((unsigned)(unsigned short)s_hl[row][col]) << 16);
                float rg = sigmoidf_(I[0][m][r] + G[0][m][r]);
                float z  = sigmoidf_(I[1][m][r] + G[1][m][r]);
                float nn = tanhf_(I[2][m][r] + rg * G[2][m][r]);
                hbuf[(size_t)n * 64 + col] = (1.0f - z) * nn + z * hold;
            }
        }
}

// Set2Set LSTM step, one block (256 thr) per graph
__global__ void k_lstm(const float* __restrict__ q_star, float* __restrict__ qh, float* __restrict__ qc,
                       const float* __restrict__ l_wihT, const float* __restrict__ l_whhT,
                       const float* __restrict__ l_bih, const float* __restrict__ l_bhh) {
    __shared__ float s_qs[128];
    __shared__ float s_qh[64];
    __shared__ float s_g[256];
    int b = blockIdx.x;
    int j = threadIdx.x;
    if (j < 128) s_qs[j] = q_star[b * 128 + j];
    else if (j < 192) s_qh[j - 128] = qh[b * 64 + (j - 128)];
    __syncthreads();
    float g = l_bih[j] + l_bhh[j];
#pragma unroll 8
    for (int i = 0; i < 128; ++i) g = fmaf(s_qs[i], l_wihT[i * 256 + j], g);
#pragma unroll 8
    for (int i = 0; i < 64; ++i)  g = fmaf(s_qh[i], l_whhT[i * 256 + j], g);
    s_g[j] = g;
    __syncthreads();
    if (j < 64) {
        float ci = sigmoidf_(s_g[j]);
        float cf = sigmoidf_(s_g[64 + j]);
        float cg = tanhf_(s_g[128 + j]);
        float co = sigmoidf_(s_g[192 + j]);
        float c = cf * qc[b * 64 + j] + ci * cg;
        qc[b * 64 + j] = c;
        qh[b * 64 + j] = co * tanhf_(c);
    }
}

// per-graph online-softmax attention. 1 wave/graph.
__global__ void k_attention(const float* __restrict__ hbuf, const float* __restrict__ qh,
                            const int* __restrict__ offs, float* __restrict__ q_star) {
    int tid = threadIdx.x;
    int w = tid >> 6, lane = tid & 63;
    int b = blockIdx.x * 4 + w;
    int s = offs[b], e = offs[b + 1];
    float qv = qh[b * 64 + lane];
    float mx = -1e30f, l = 0.0f, racc = 0.0f;
    for (int n = s; n < e; ++n) {
        float xv = hbuf[n * 64 + lane];
        float prod = xv * qv;
#pragma unroll
        for (int off = 32; off > 0; off >>= 1) prod += __shfl_xor(prod, off);
        float mnew = fmaxf(mx, prod);
        float scale = __expf(mx - mnew);
        float wgt = __expf(prod - mnew);
        l = l * scale + wgt;
        racc = racc * scale + wgt * xv;
        mx = mnew;
    }
    float r = (e > s) ? (racc / l) : 0.0f;
    q_star[b * 128 + lane] = qv;
    q_star[b * 128 + 64 + lane] = r;
}

// readout MLP, 1 wave/graph
__global__ void k_readout(const float* __restrict__ q_star, const float* __restrict__ t,
                          const float* __restrict__ p, const float* __restrict__ W1,
                          const float* __restrict__ b1, const float* __restrict__ W2,
                          const float* __restrict__ b2, const float* __restrict__ W3,
                          const float* __restrict__ b3, float* __restrict__ y) {
    __shared__ float s_qs[4][128];
    __shared__ float s_y[4][64];
    int tid = threadIdx.x;
    int w = tid >> 6, j = tid & 63;
    int b = blockIdx.x * 4 + w;
    s_qs[w][j] = q_star[b * 128 + j];
    s_qs[w][64 + j] = q_star[b * 128 + 64 + j];
    __syncthreads();
    float acc = b1[j];
#pragma unroll 8
    for (int i = 0; i < 128; ++i) acc = fmaf(s_qs[w][i], W1[i * 64 + j], acc);
    acc = fmaf(t[b], W1[128 * 64 + j], acc);
    acc = fmaf(p[b], W1[129 * 64 + j], acc);
    acc = fmaxf(acc, 0.0f);
    s_y[w][j] = acc;
    __syncthreads();
    float acc2 = b2[j];
#pragma unroll 8
    for (int i = 0; i < 64; ++i) acc2 = fmaf(s_y[w][i], W2[i * 64 + j], acc2);
    acc2 = fmaxf(acc2, 0.0f);
    float part = acc2 * W3[j];
#pragma unroll
    for (int off = 32; off > 0; off >>= 1) part += __shfl_xor(part, off);
    if (j == 0) y[b] = part + b3[0];
}

extern "C" void kernel_launch(void* const* d_in, const int* in_sizes, int n_in,
                              void* d_out, int out_size, void* d_ws, size_t ws_size,
                              hipStream_t stream) {
    const float* x     = (const float*)d_in[0];
    const int*   ei    = (const int*)  d_in[1];
    const float* ea    = (const float*)d_in[2];
    const int*   batch = (const int*)  d_in[3];
    const float* t     = (const float*)d_in[4];
    const float* p     = (const float*)d_in[5];
    const float* W0    = (const float*)d_in[7];
    const float* b0    = (const float*)d_in[8];
    const float* We1   = (const float*)d_in[9];
    const float* be1   = (const float*)d_in[10];
    const float* We2   = (const float*)d_in[11];
    const float* be2   = (const float*)d_in[12];
    const float* Wroot = (const float*)d_in[13];
    const float* bconv = (const float*)d_in[14];
    const float* gwih  = (const float*)d_in[15];
    const float* gwhh  = (const float*)d_in[16];
    const float* gbih  = (const float*)d_in[17];
    const float* gbhh  = (const float*)d_in[18];
    const float* lwih  = (const float*)d_in[19];
    const float* lwhh  = (const float*)d_in[20];
    const float* lbih  = (const float*)d_in[21];
    const float* lbhh  = (const float*)d_in[22];
    const float* W1    = (const float*)d_in[23];
    const float* b1    = (const float*)d_in[24];
    const float* W2    = (const float*)d_in[25];
    const float* b2    = (const float*)d_in[26];
    const float* W3    = (const float*)d_in[27];
    const float* b3    = (const float*)d_in[28];
    float* y = (float*)d_out;

    char* ws = (char*)d_ws;
    size_t off = 0;
    auto alloc = [&](size_t nbytes) {
        void* ptr = (void*)(ws + off);
        off += align_up(nbytes, 256);
        return ptr;
    };
    float* hbuf   = (float*)alloc((size_t)N_NODES * 64 * 4);
    float* reb    = (float*)alloc((size_t)N_EDGES * 64 * 4);
    float* msg    = (float*)alloc((size_t)N_EDGES * 64 * 4);
    short* We2b   = (short*)alloc((size_t)65 * 4096 * 2);
    short* WB1h   = (short*)alloc(16384 * 2);
    short* WB1l   = (short*)alloc(16384 * 2);
    short* WB2h   = (short*)alloc(12288 * 2);
    short* WB2l   = (short*)alloc(12288 * 2);
    float* lwihT  = (float*)alloc(128 * 256 * 4);
    float* lwhhT  = (float*)alloc(64 * 256 * 4);
    float* qh     = (float*)alloc(NB * 64 * 4);
    float* qc     = (float*)alloc(NB * 64 * 4);
    float* qstar  = (float*)alloc(NB * 128 * 4);
    int*   offs   = (int*)  alloc((NB + 1) * 4);
    int*   deg    = (int*)  alloc(N_NODES * 4);
    int*   rowptr = (int*)  alloc((N_NODES + 1) * 4);
    int*   cursor = (int*)  alloc(N_NODES * 4);
    int*   perm   = (int*)  alloc(N_EDGES * 4);

    // ---- prep ----
    k_transpose<<<(256 * 128 + 255) / 256, 256, 0, stream>>>(lwih, lwihT, 256, 128);
    k_transpose<<<(256 * 64 + 255) / 256, 256, 0, stream>>>(lwhh, lwhhT, 256, 64);
    k_we2b<<<65 * 4096 / 256, 256, 0, stream>>>(We2, be2, We2b);
    k_wsplit<<<(28672 + 255) / 256, 256, 0, stream>>>(Wroot, gwhh, gwih, WB1h, WB1l, WB2h, WB2l);
    k_offsets<<<5, 256, 0, stream>>>(batch, offs);
    hipMemsetAsync(qh, 0, (size_t)(NB * 64 + NB * 64 + NB * 128) * 4, stream); // qh|qc|qstar contiguous
    hipMemsetAsync(deg, 0, (size_t)N_NODES * 4, stream);
    k_count<<<(N_EDGES + 255) / 256, 256, 0, stream>>>(ei, deg);
    k_scan<<<1, 1024, 0, stream>>>(deg, rowptr, cursor);
    k_fill<<<(N_EDGES + 255) / 256, 256, 0, stream>>>(ei, cursor, perm);

    // ---- encoder ----
    k_node_init<<<N_NODES / 4, 256, 0, stream>>>(x, W0, b0, hbuf);
    k_edge_feat<<<N_EDGES / 4, 256, 0, stream>>>(ea, We1, be1, reb);

    // ---- 4 message-passing + GRU iterations ----
    for (int it = 0; it < 4; ++it) {
        k_msg_mfma<<<(N_EDGES + 63) / 64, 256, 0, stream>>>(hbuf, reb, We2b, ei, msg);
        k_node_update<<<(N_NODES + 63) / 64, 256, 0, stream>>>(hbuf, msg, rowptr, perm,
                                                               WB1h, WB1l, WB2h, WB2l,
                                                               bconv, gbih, gbhh);
    }

    // ---- Set2Set, 3 steps ----
    for (int itr = 0; itr < 3; ++itr) {
        k_lstm<<<NB, 256, 0, stream>>>(qstar, qh, qc, lwihT, lwhhT, lbih, lbhh);
        k_attention<<<NB / 4, 256, 0, stream>>>(hbuf, qh, offs, qstar);
    }

    // ---- readout ----
    k_readout<<<NB / 4, 256, 0, stream>>>(qstar, t, p, W1, b1, W2, b2, W3, b3, y);
}